// Round 12
// baseline (217.128 us; speedup 1.0000x reference)
//
#include <hip/hip_runtime.h>
#include <hip/hip_bf16.h>
#include <stdint.h>

typedef unsigned short u16;
typedef __attribute__((ext_vector_type(4))) float f32x4;
typedef __attribute__((ext_vector_type(8))) short bf16x8;
typedef __attribute__((ext_vector_type(4))) unsigned int u32x4;

#define GLL16(src, dst) __builtin_amdgcn_global_load_lds( \
    (const __attribute__((address_space(1))) void*)(src), \
    (__attribute__((address_space(3))) void*)(dst), 16, 0, 0)

static __device__ __forceinline__ u16 f2bf(float x) {
    uint32_t u = __builtin_bit_cast(uint32_t, x);
    u += 0x7fffu + ((u >> 16) & 1u);
    return (u16)(u >> 16);
}

static __device__ __forceinline__ uint32_t cvtpk(float lo, float hi) {
    uint32_t r;
    asm("v_cvt_pk_bf16_f32 %0, %1, %2" : "=v"(r) : "v"(lo), "v"(hi));
    return r;
}

// ---------------- fp32 -> bf16 conversion ----------------
__global__ __launch_bounds__(256) void cvt_f32_bf16(
        const float* __restrict__ in, u16* __restrict__ out, int n4) {
    int i = blockIdx.x * 256 + threadIdx.x;
    if (i >= n4) return;
    float4 v = ((const float4*)in)[i];
    ushort4 o;
    o.x = f2bf(v.x); o.y = f2bf(v.y); o.z = f2bf(v.z); o.w = f2bf(v.w);
    ((ushort4*)out)[i] = o;
}

// all four weight matrices in one dispatch; dst rows: [Wq | Wk | Wv | Wo]
__global__ __launch_bounds__(256) void cvt_w4(
        const float* __restrict__ s0, const float* __restrict__ s1,
        const float* __restrict__ s2, const float* __restrict__ s3,
        u16* __restrict__ dst) {
    int wsel = blockIdx.y;
    const float* s = (wsel == 0) ? s0 : (wsel == 1) ? s1 : (wsel == 2) ? s2 : s3;
    int i = blockIdx.x * 256 + threadIdx.x;
    float4 v = ((const float4*)s)[i];
    ushort4 o;
    o.x = f2bf(v.x); o.y = f2bf(v.y); o.z = f2bf(v.z); o.w = f2bf(v.w);
    ((ushort4*)(dst + (size_t)wsel * 1024 * 1024))[i] = o;
}

// ---------------- phased big-tile GEMM (T3+T4 schedule) ----------------
// BM=256, BN=128, BK=64, 512 threads = 8 waves (2M x 4N), per-wave C 128x32.
// Double-buffered LDS (96 KB, 1 block/CU). Per K-tile: 4 phases, each
// {ds_read A-subtile + issue half-stage GLL16 -> s_barrier -> 8 MFMA -> s_barrier}.
// All intra-iter reads hit the STABLE buffer (writes go to the other one), so
// phase barriers are scheduling-only. One vmcnt(0)+barrier gate per K-tile;
// the gated loads were issued 2-4 phases (>600cy) earlier.
// MODE 0: fused QKV (Q pre-scaled by log2e/32; V scattered s'-permuted).
// MODE 1: fp32 out (output projection).
template <int MODE>
__global__ __launch_bounds__(512, 2) void gemm2(
        const u16* __restrict__ A, const u16* __restrict__ W,
        const float* __restrict__ b0, const float* __restrict__ b1,
        const float* __restrict__ b2,
        void* __restrict__ o0, void* __restrict__ o1, void* __restrict__ o2) {
    __shared__ __align__(16) u16 As[2][256 * 64];   // 64 KB
    __shared__ __align__(16) u16 Bs[2][128 * 64];   // 32 KB
    const int tid = threadIdx.x;
    const int lane = tid & 63;
    const int w = tid >> 6, wm = w >> 2, wn = w & 3;
    const int l15 = lane & 15, l4 = lane >> 4;
    constexpr int NXB = (MODE == 0) ? 24 : 8;       // N / 128
    constexpr int CPX = (MODE == 0) ? 96 : 32;      // blocks per XCD
    int v = (blockIdx.x & 7) * CPX + (blockIdx.x >> 3);
    int vy = v / NXB, vx = v - vy * NXB;
    const int m0 = vy * 256, n0 = vx * 128;
    const float SC2 = 0.03125f * 1.44269504088896f;

#define G2_STAGE_A(buf, kt, i) do {                                        \
    int c_ = tid + (i) * 512;                                              \
    int row_ = c_ >> 3, slot_ = c_ & 7;                                    \
    int cc_ = slot_ ^ (row_ & 7);                                          \
    GLL16(A + (size_t)(m0 + row_) * 1024 + (kt) + cc_ * 8, As[buf] + c_ * 8); \
} while (0)
#define G2_STAGE_B(buf, kt, i) do {                                        \
    int c_ = tid + (i) * 512;                                              \
    int row_ = c_ >> 3, slot_ = c_ & 7;                                    \
    int cc_ = slot_ ^ (row_ & 7);                                          \
    GLL16(W + (size_t)(n0 + row_) * 1024 + (kt) + cc_ * 8, Bs[buf] + c_ * 8); \
} while (0)

    f32x4 acc[8][2];
#pragma unroll
    for (int mi = 0; mi < 8; mi++)
#pragma unroll
        for (int nj = 0; nj < 2; nj++) acc[mi][nj] = f32x4{0.f, 0.f, 0.f, 0.f};

    // prologue: tile 0 -> buf 0 (6 GLL16/thread)
    G2_STAGE_A(0, 0, 0); G2_STAGE_A(0, 0, 1); G2_STAGE_A(0, 0, 2); G2_STAGE_A(0, 0, 3);
    G2_STAGE_B(0, 0, 0); G2_STAGE_B(0, 0, 1);

    for (int t = 0; t < 16; ++t) {
        const int cur = t & 1, nxt = cur ^ 1;
        const int ktn = (t + 1) * 64;

        // gate: previous iteration's stages into buf[cur] must have landed
        asm volatile("s_waitcnt vmcnt(0)" ::: "memory");
        __builtin_amdgcn_s_barrier();
        __builtin_amdgcn_sched_barrier(0);

        // B fragments for the whole tile (4 ds_read_b128), live across phases
        bf16x8 bfr[2][2];
#pragma unroll
        for (int nj = 0; nj < 2; nj++)
#pragma unroll
            for (int kh = 0; kh < 2; kh++) {
                int row = wn * 32 + nj * 16 + l15;
                int slot = (kh * 4 + l4) ^ (row & 7);
                bfr[nj][kh] = *(const bf16x8*)(Bs[cur] + row * 64 + slot * 8);
            }

#pragma unroll
        for (int p = 0; p < 4; p++) {
            bf16x8 af[2][2];
#pragma unroll
            for (int m2 = 0; m2 < 2; m2++)
#pragma unroll
                for (int kh = 0; kh < 2; kh++) {
                    int mi = p * 2 + m2;
                    int row = wm * 128 + mi * 16 + l15;
                    int slot = (kh * 4 + l4) ^ (row & 7);
                    af[m2][kh] = *(const bf16x8*)(As[cur] + row * 64 + slot * 8);
                }
            if (t != 15) {
                if (p == 0) { G2_STAGE_A(nxt, ktn, 0); G2_STAGE_A(nxt, ktn, 1); }
                else if (p == 1) { G2_STAGE_A(nxt, ktn, 2); G2_STAGE_A(nxt, ktn, 3); }
                else if (p == 2) { G2_STAGE_B(nxt, ktn, 0); G2_STAGE_B(nxt, ktn, 1); }
            }
            __builtin_amdgcn_s_barrier();
            __builtin_amdgcn_s_setprio(1);
#pragma unroll
            for (int m2 = 0; m2 < 2; m2++)
#pragma unroll
                for (int nj = 0; nj < 2; nj++)
#pragma unroll
                    for (int kh = 0; kh < 2; kh++)
                        acc[p * 2 + m2][nj] = __builtin_amdgcn_mfma_f32_16x16x32_bf16(
                            af[m2][kh], bfr[nj][kh], acc[p * 2 + m2][nj], 0, 0, 0);
            __builtin_amdgcn_s_setprio(0);
            __builtin_amdgcn_s_barrier();
        }
    }

    // ---- epilogue ----
#pragma unroll
    for (int nj = 0; nj < 2; nj++) {
        int col = n0 + wn * 32 + nj * 16 + l15;
        if (MODE == 1) {
            float bvv = b0[col];
            float* out = (float*)o0;
#pragma unroll
            for (int mi = 0; mi < 8; mi++) {
                int rowb = m0 + wm * 128 + mi * 16 + l4 * 4;
#pragma unroll
                for (int r = 0; r < 4; r++)
                    out[(size_t)(rowb + r) * 1024 + col] = acc[mi][nj][r] + bvv;
            }
        } else {
            int sel = col >> 10;   // uniform per block (n0 is 128-aligned)
            float bvv = (sel == 0) ? b0[col] : (sel == 1) ? b1[col - 1024] : b2[col - 2048];
#pragma unroll
            for (int mi = 0; mi < 8; mi++) {
                int rowb = m0 + wm * 128 + mi * 16 + l4 * 4;
                if (sel == 0) {
                    u16* out = (u16*)o0;
#pragma unroll
                    for (int r = 0; r < 4; r++)
                        out[(size_t)(rowb + r) * 1024 + col] = f2bf((acc[mi][nj][r] + bvv) * SC2);
                } else if (sel == 1) {
                    u16* out = (u16*)o1;
#pragma unroll
                    for (int r = 0; r < 4; r++)
                        out[(size_t)(rowb + r) * 1024 + (col - 1024)] = f2bf(acc[mi][nj][r] + bvv);
                } else {
                    u16* out = (u16*)o2;
                    int cc2 = col - 2048;
                    int g64 = m0 + wm * 128 + (mi >> 2) * 64;   // 64-row group base
                    int i64 = mi & 3;
                    int bb = g64 >> 11;
                    int sp = (g64 & 2047) + (i64 >> 1) * 32 + l4 * 8 + (i64 & 1) * 4;
                    int hh = cc2 >> 6, dd = cc2 & 63;
                    ushort4 o;
                    o.x = f2bf(acc[mi][nj][0] + bvv);
                    o.y = f2bf(acc[mi][nj][1] + bvv);
                    o.z = f2bf(acc[mi][nj][2] + bvv);
                    o.w = f2bf(acc[mi][nj][3] + bvv);
                    *(ushort4*)(out + ((size_t)((bb * 16 + hh) * 64 + dd)) * 2048 + sp) = o;
                }
            }
        }
    }
#undef G2_STAGE_A
#undef G2_STAGE_B
}

// ---------------- fused flash attention (R8-proven version, reverted) ----------------
// 1D grid 1024, XCD swizzle (K/V L2-resident). 4 waves x 32 q-rows.
// K/V double-buffered LDS via global_load_lds, one __syncthreads/iter.
// Q pre-scaled by log2(e)/32 -> QK^T emits base-2 scores; defer-max keeps
// m_run == 0 (wave-uniform fast path); V s'-permuted so PV B-operand is
// lane-local P quads. Denominator via ones-MFMA.
// (R10/R11's 256-q variant spilled — 128 arch-VGPR split on the unified RF —
// and netted negative; reverted per pre-commitment.)
__global__ __launch_bounds__(256, 3) void attn_fused(
        const u16* __restrict__ Q, const u16* __restrict__ K,
        const u16* __restrict__ Vt, const float* __restrict__ mask,
        u16* __restrict__ ctx) {
    __shared__ __align__(16) u16 Ks[2][64 * 64];    // [kv][d], swizzled slots
    __shared__ __align__(16) u16 Vs[2][64 * 64];    // [d][s'], swizzled slots

    const int tid = threadIdx.x, lane = tid & 63, w = tid >> 6;
    const int l15 = lane & 15, l4 = lane >> 4;
    const int bid = blockIdx.x;
    const int inner = bid >> 3;
    const int bh = ((inner >> 4) << 3) | (bid & 7);
    const int b = bh >> 4, h = bh & 15;
    const int qw = (inner & 15) * 128 + w * 32;
    const float THR2 = 8.0f;

    const u16* Qg = Q + (size_t)b * 2048 * 1024 + h * 64;
    const u16* Kg = K + (size_t)b * 2048 * 1024 + h * 64;
    const u16* Vg = Vt + (size_t)bh * 64 * 2048;
    const float* mp = mask + b * 2048;

    // ---- wave-redundant mask scan: 64 lanes x 8 float4 = 2048 ----
    bool anym;
    {
        bool bad = false;
#pragma unroll
        for (int i = 0; i < 8; i++) {
            float4 a = ((const float4*)mp)[lane * 8 + i];
            bad |= (a.x == 0.f) | (a.y == 0.f) | (a.z == 0.f) | (a.w == 0.f);
        }
        anym = (__ballot(bad) != 0ull);
    }

#define STAGE_KV(buf, kvbase) do {                                         \
    _Pragma("unroll")                                                      \
    for (int i_ = 0; i_ < 2; i_++) {                                       \
        int c_ = tid + i_ * 256;                                           \
        int row_ = c_ >> 3, slot_ = c_ & 7;                                \
        int cc_ = slot_ ^ (row_ & 7);                                      \
        GLL16(Kg + (size_t)((kvbase) + row_) * 1024 + cc_ * 8, Ks[buf] + c_ * 8); \
    }                                                                      \
    _Pragma("unroll")                                                      \
    for (int i_ = 0; i_ < 2; i_++) {                                       \
        int c_ = tid + i_ * 256;                                           \
        int row_ = c_ >> 3, slot_ = c_ & 7;                                \
        int cc_ = slot_ ^ (row_ & 7);                                      \
        GLL16(Vg + (size_t)row_ * 2048 + (kvbase) + cc_ * 8, Vs[buf] + c_ * 8); \
    }                                                                      \
} while (0)

    // hoist Q fragments (B-operand layout), already scaled by log2e/32
    bf16x8 qfr[2][2];
#pragma unroll
    for (int qi = 0; qi < 2; qi++)
#pragma unroll
        for (int kf = 0; kf < 2; kf++)
            qfr[qi][kf] = *(const bf16x8*)(Qg + (size_t)(qw + qi * 16 + l15) * 1024 + kf * 32 + l4 * 8);

    // q-mask 0/1 flag (cold path only)
    float mq01[2];
#pragma unroll
    for (int qi = 0; qi < 2; qi++)
        mq01[qi] = (mp[qw + qi * 16 + l15] != 0.f) ? 1.f : 0.f;

    float m_run[2] = {0.f, 0.f};
    f32x4 acc_l[2];      // denominator via ones-MFMA
    f32x4 oaccT[4][2];   // O^T: [d-frag][q-frag]
#pragma unroll
    for (int qi = 0; qi < 2; qi++) acc_l[qi] = f32x4{0.f, 0.f, 0.f, 0.f};
#pragma unroll
    for (int df = 0; df < 4; df++)
#pragma unroll
        for (int qi = 0; qi < 2; qi++) oaccT[df][qi] = f32x4{0.f, 0.f, 0.f, 0.f};

    const u32x4 ones4 = u32x4{0x3F803F80u, 0x3F803F80u, 0x3F803F80u, 0x3F803F80u};
    const bf16x8 ones = __builtin_bit_cast(bf16x8, ones4);

    STAGE_KV(0, 0);
    __syncthreads();

    for (int it = 0; it < 32; ++it) {
        const int cur = it & 1;
        const int kv0 = it * 64;

        if (it != 31) STAGE_KV(cur ^ 1, kv0 + 64);

        // ---- S^T = K Q^T (emits base-2 scores; Q pre-scaled) ----
        bf16x8 kfr[4][2];
#pragma unroll
        for (int kvf = 0; kvf < 4; kvf++)
#pragma unroll
            for (int kf = 0; kf < 2; kf++) {
                int row = kvf * 16 + l15;
                int slot = (kf * 4 + l4) ^ (row & 7);
                kfr[kvf][kf] = *(const bf16x8*)(Ks[cur] + row * 64 + slot * 8);
            }
        f32x4 p[4][2];
#pragma unroll
        for (int kvf = 0; kvf < 4; kvf++)
#pragma unroll
            for (int qi = 0; qi < 2; qi++) p[kvf][qi] = f32x4{0.f, 0.f, 0.f, 0.f};
        __builtin_amdgcn_s_setprio(1);
#pragma unroll
        for (int kvf = 0; kvf < 4; kvf++)
#pragma unroll
            for (int qi = 0; qi < 2; qi++)
#pragma unroll
                for (int kf = 0; kf < 2; kf++)
                    p[kvf][qi] = __builtin_amdgcn_mfma_f32_16x16x32_bf16(kfr[kvf][kf], qfr[qi][kf], p[kvf][qi], 0, 0, 0);
        __builtin_amdgcn_s_setprio(0);

        // ---- cold masked path: p = p*mq01 + kbias ----
        if (anym) {
            float4 mkv[4];
#pragma unroll
            for (int kvf = 0; kvf < 4; kvf++)
                mkv[kvf] = ((const float4*)(mp + kv0))[kvf * 4 + l4];
#pragma unroll
            for (int qi = 0; qi < 2; qi++)
#pragma unroll
                for (int kvf = 0; kvf < 4; kvf++)
#pragma unroll
                    for (int r = 0; r < 4; r++) {
                        float bb = (mkv[kvf][r] != 0.f) ? 0.f : -1e12f;
                        p[kvf][qi][r] = __builtin_fmaf(p[kvf][qi][r], mq01[qi], bb);
                    }
        }

        // ---- lane-local maxima; guard vs m_run + THR ----
        float t[2];
#pragma unroll
        for (int qi = 0; qi < 2; qi++) {
            float a0 = fmaxf(fmaxf(p[0][qi][0], p[0][qi][1]), fmaxf(p[0][qi][2], p[0][qi][3]));
            float a1 = fmaxf(fmaxf(p[1][qi][0], p[1][qi][1]), fmaxf(p[1][qi][2], p[1][qi][3]));
            float a2 = fmaxf(fmaxf(p[2][qi][0], p[2][qi][1]), fmaxf(p[2][qi][2], p[2][qi][3]));
            float a3 = fmaxf(fmaxf(p[3][qi][0], p[3][qi][1]), fmaxf(p[3][qi][2], p[3][qi][3]));
            t[qi] = fmaxf(fmaxf(a0, a1), fmaxf(a2, a3));
        }
        if (!__all((t[0] <= m_run[0] + THR2) && (t[1] <= m_run[1] + THR2))) {
            // cold rescale: cross-lane max, update m_run, scale accumulators
#pragma unroll
            for (int qi = 0; qi < 2; qi++) {
                float tt = fmaxf(t[qi], __shfl_xor(t[qi], 16));
                tt = fmaxf(tt, __shfl_xor(tt, 32));
                float mn = fmaxf(m_run[qi], tt);
                float sc = __builtin_amdgcn_exp2f(m_run[qi] - mn);
                m_run[qi] = mn;
                acc_l[qi] *= sc;
#pragma unroll
                for (int df = 0; df < 4; df++) oaccT[df][qi] *= sc;
            }
        }
        // ---- exp2; m_run==0 fast path has no subtract ----
        if (__all((m_run[0] == 0.f) & (m_run[1] == 0.f))) {
#pragma unroll
            for (int qi = 0; qi < 2; qi++)
#pragma unroll
                for (int kvf = 0; kvf < 4; kvf++)
#pragma unroll
                    for (int r = 0; r < 4; r++)
                        p[kvf][qi][r] = __builtin_amdgcn_exp2f(p[kvf][qi][r]);
        } else {
#pragma unroll
            for (int qi = 0; qi < 2; qi++)
#pragma unroll
                for (int kvf = 0; kvf < 4; kvf++)
#pragma unroll
                    for (int r = 0; r < 4; r++)
                        p[kvf][qi][r] = __builtin_amdgcn_exp2f(p[kvf][qi][r] - m_run[qi]);
        }

        // ---- pb = lane-local P quads packed to bf16 ----
        bf16x8 pb[2][2];
#pragma unroll
        for (int qi = 0; qi < 2; qi++)
#pragma unroll
            for (int kf = 0; kf < 2; kf++) {
                u32x4 tq;
                tq.x = cvtpk(p[2 * kf][qi][0], p[2 * kf][qi][1]);
                tq.y = cvtpk(p[2 * kf][qi][2], p[2 * kf][qi][3]);
                tq.z = cvtpk(p[2 * kf + 1][qi][0], p[2 * kf + 1][qi][1]);
                tq.w = cvtpk(p[2 * kf + 1][qi][2], p[2 * kf + 1][qi][3]);
                pb[qi][kf] = __builtin_bit_cast(bf16x8, tq);
            }

        // V fragments after softmax (kept out of the VALU-phase live set)
        bf16x8 vfr[4][2];
#pragma unroll
        for (int df = 0; df < 4; df++)
#pragma unroll
            for (int kf = 0; kf < 2; kf++) {
                int row = df * 16 + l15;
                int slot = (kf * 4 + l4) ^ (row & 7);
                vfr[df][kf] = *(const bf16x8*)(Vs[cur] + row * 64 + slot * 8);
            }

        // ---- O^T += V^T P^T ; l += ones^T P^T ----
        __builtin_amdgcn_s_setprio(1);
#pragma unroll
        for (int df = 0; df < 4; df++)
#pragma unroll
            for (int qi = 0; qi < 2; qi++)
#pragma unroll
                for (int kf = 0; kf < 2; kf++)
                    oaccT[df][qi] = __builtin_amdgcn_mfma_f32_16x16x32_bf16(vfr[df][kf], pb[qi][kf], oaccT[df][qi], 0, 0, 0);
#pragma unroll
        for (int qi = 0; qi < 2; qi++)
#pragma unroll
            for (int kf = 0; kf < 2; kf++)
                acc_l[qi] = __builtin_amdgcn_mfma_f32_16x16x32_bf16(ones, pb[qi][kf], acc_l[qi], 0, 0, 0);
        __builtin_amdgcn_s_setprio(0);

        __syncthreads();   // drains prefetch vmcnt + protects both dbuf halves
    }

    // ---- epilogue: ctx[token][h*64+d] = O^T / l ----
#pragma unroll
    for (int qi = 0; qi < 2; qi++) {
        float rl = 1.0f / acc_l[qi][0];
        int tok = qw + qi * 16 + l15;
#pragma unroll
        for (int df = 0; df < 4; df++) {
            uint2 o;
            o.x = cvtpk(oaccT[df][qi][0] * rl, oaccT[df][qi][1] * rl);
            o.y = cvtpk(oaccT[df][qi][2] * rl, oaccT[df][qi][3] * rl);
            *(uint2*)(ctx + (size_t)(b * 2048 + tok) * 1024 + h * 64 + df * 16 + l4 * 4) = o;
        }
    }
#undef STAGE_KV
}

extern "C" void kernel_launch(void* const* d_in, const int* in_sizes, int n_in,
                              void* d_out, int out_size, void* d_ws, size_t ws_size,
                              hipStream_t stream) {
    const float* hs    = (const float*)d_in[0];
    const float* masks = (const float*)d_in[1];
    const float* Wq = (const float*)d_in[2];
    const float* bq = (const float*)d_in[3];
    const float* Wk = (const float*)d_in[4];
    const float* bk = (const float*)d_in[5];
    const float* Wv = (const float*)d_in[6];
    const float* bv = (const float*)d_in[7];
    const float* Wo = (const float*)d_in[8];
    const float* bo = (const float*)d_in[9];

    const int NT = 4 * 2048;   // 8192 tokens
    const int H = 1024;

    u16* hs_b = (u16*)d_ws;                       // [8192,1024]
    u16* w_b  = hs_b + (size_t)NT * H;            // [Wq|Wk|Wv|Wo] 4x[1024,1024]
    u16* wo_b = w_b + (size_t)3 * H * H;
    u16* Qb   = w_b + (size_t)4 * H * H;          // [8192,1024] (pre-scaled)
    u16* Kb   = Qb + (size_t)NT * H;              // [8192,1024]
    u16* Vtb  = Kb + (size_t)NT * H;              // [64][64][2048] s'-permuted
    u16* Cb   = hs_b;                             // attn output reuses hidden buffer

    cvt_f32_bf16<<<NT * H / 1024, 256, 0, stream>>>(hs, hs_b, NT * H / 4);
    cvt_w4<<<dim3(H * H / 1024, 4), 256, 0, stream>>>(Wq, Wk, Wv, Wo, w_b);

    // fused QKV: M=8192, N=3072 -> 32 x 24 = 768 blocks (3 exact rounds/CU)
    gemm2<0><<<768, 512, 0, stream>>>(hs_b, w_b, bq, bk, bv, Qb, Kb, Vtb);

    attn_fused<<<1024, 256, 0, stream>>>(Qb, Kb, Vtb, masks, Cb);

    // output projection: M=8192, N=1024 -> 32 x 8 = 256 blocks (1 exact round)
    gemm2<1><<<256, 512, 0, stream>>>(Cb, wo_b, bo, nullptr, nullptr,
                                      (void*)d_out, nullptr, nullptr);
}

// Round 13
// 203.096 us; speedup vs baseline: 1.0691x; 1.0691x over previous
//
#include <hip/hip_runtime.h>
#include <hip/hip_bf16.h>
#include <stdint.h>

typedef unsigned short u16;
typedef __attribute__((ext_vector_type(4))) float f32x4;
typedef __attribute__((ext_vector_type(8))) short bf16x8;
typedef __attribute__((ext_vector_type(4))) unsigned int u32x4;

#define GLL16(src, dst) __builtin_amdgcn_global_load_lds( \
    (const __attribute__((address_space(1))) void*)(src), \
    (__attribute__((address_space(3))) void*)(dst), 16, 0, 0)

static __device__ __forceinline__ u16 f2bf(float x) {
    uint32_t u = __builtin_bit_cast(uint32_t, x);
    u += 0x7fffu + ((u >> 16) & 1u);
    return (u16)(u >> 16);
}

static __device__ __forceinline__ uint32_t cvtpk(float lo, float hi) {
    uint32_t r;
    asm("v_cvt_pk_bf16_f32 %0, %1, %2" : "=v"(r) : "v"(lo), "v"(hi));
    return r;
}

// ---------------- fp32 -> bf16 conversion ----------------
__global__ __launch_bounds__(256) void cvt_f32_bf16(
        const float* __restrict__ in, u16* __restrict__ out, int n4) {
    int i = blockIdx.x * 256 + threadIdx.x;
    if (i >= n4) return;
    float4 v = ((const float4*)in)[i];
    ushort4 o;
    o.x = f2bf(v.x); o.y = f2bf(v.y); o.z = f2bf(v.z); o.w = f2bf(v.w);
    ((ushort4*)out)[i] = o;
}

// all four weight matrices in one dispatch; dst rows: [Wq | Wk | Wv | Wo]
__global__ __launch_bounds__(256) void cvt_w4(
        const float* __restrict__ s0, const float* __restrict__ s1,
        const float* __restrict__ s2, const float* __restrict__ s3,
        u16* __restrict__ dst) {
    int wsel = blockIdx.y;
    const float* s = (wsel == 0) ? s0 : (wsel == 1) ? s1 : (wsel == 2) ? s2 : s3;
    int i = blockIdx.x * 256 + threadIdx.x;
    float4 v = ((const float4*)s)[i];
    ushort4 o;
    o.x = f2bf(v.x); o.y = f2bf(v.y); o.z = f2bf(v.z); o.w = f2bf(v.w);
    ((ushort4*)(dst + (size_t)wsel * 1024 * 1024))[i] = o;
}

// ---------------- fused QKV GEMM (R8-proven, reverted from R12's regression) ----------------
__global__ __launch_bounds__(256, 2) void gemm_qkv(
        const u16* __restrict__ A, const u16* __restrict__ W,
        const float* __restrict__ bq, const float* __restrict__ bk,
        const float* __restrict__ bv,
        u16* __restrict__ Qo, u16* __restrict__ Ko, u16* __restrict__ Vo) {
    __shared__ __align__(16) u16 As[2][128 * 32];
    __shared__ __align__(16) u16 Bs[2][128 * 32];
    const int tid = threadIdx.x;
    const int lane = tid & 63;
    const int w = tid >> 6, wm = w >> 1, wn = w & 1;
    const int l15 = lane & 15, l4 = lane >> 4;
    int v = (blockIdx.x & 7) * 192 + (blockIdx.x >> 3);
    int vy = v / 24, vx = v - vy * 24;
    const int m0 = vy * 128, n0 = vx * 128;
    const float SC2 = 0.03125f * 1.44269504088896f;

    f32x4 acc[4][4];
#pragma unroll
    for (int i = 0; i < 4; i++)
#pragma unroll
        for (int j = 0; j < 4; j++) acc[i][j] = f32x4{0.f, 0.f, 0.f, 0.f};

#define QKV_STAGE(buf, kt) do {                                            \
    _Pragma("unroll")                                                      \
    for (int i_ = 0; i_ < 2; i_++) {                                       \
        int c_ = tid + i_ * 256;                                           \
        int row_ = c_ >> 2, slot_ = c_ & 3;                                \
        int cc_ = slot_ ^ ((row_ >> 1) & 3);                               \
        GLL16(A + (size_t)(m0 + row_) * 1024 + (kt) + cc_ * 8, As[buf] + c_ * 8); \
    }                                                                      \
    _Pragma("unroll")                                                      \
    for (int i_ = 0; i_ < 2; i_++) {                                       \
        int c_ = tid + i_ * 256;                                           \
        int row_ = c_ >> 2, slot_ = c_ & 3;                                \
        int cc_ = slot_ ^ ((row_ >> 1) & 3);                               \
        GLL16(W + (size_t)(n0 + row_) * 1024 + (kt) + cc_ * 8, Bs[buf] + c_ * 8); \
    }                                                                      \
} while (0)

    QKV_STAGE(0, 0);
    __syncthreads();

    for (int kt = 0; kt < 1024; kt += 32) {
        const int cur = (kt >> 5) & 1;
        if (kt != 992) QKV_STAGE(cur ^ 1, kt + 32);

        bf16x8 af[4], bfr[4];
#pragma unroll
        for (int i = 0; i < 4; i++) {
            int row = wm * 64 + i * 16 + l15;
            int slot = l4 ^ ((row >> 1) & 3);
            af[i] = *(const bf16x8*)(As[cur] + row * 32 + slot * 8);
        }
#pragma unroll
        for (int j = 0; j < 4; j++) {
            int row = wn * 64 + j * 16 + l15;
            int slot = l4 ^ ((row >> 1) & 3);
            bfr[j] = *(const bf16x8*)(Bs[cur] + row * 32 + slot * 8);
        }
#pragma unroll
        for (int i = 0; i < 4; i++)
#pragma unroll
            for (int j = 0; j < 4; j++)
                acc[i][j] = __builtin_amdgcn_mfma_f32_16x16x32_bf16(af[i], bfr[j], acc[i][j], 0, 0, 0);
        __syncthreads();
    }
#undef QKV_STAGE

#pragma unroll
    for (int j = 0; j < 4; j++) {
        int col = n0 + wn * 64 + j * 16 + l15;
        int sel = col >> 10;
        float bvv = (sel == 0) ? bq[col] : (sel == 1) ? bk[col - 1024] : bv[col - 2048];
#pragma unroll
        for (int i = 0; i < 4; i++) {
            int rowb = m0 + wm * 64 + i * 16 + l4 * 4;
            if (sel == 0) {
#pragma unroll
                for (int r = 0; r < 4; r++)
                    Qo[(size_t)(rowb + r) * 1024 + col] = f2bf((acc[i][j][r] + bvv) * SC2);
            } else if (sel == 1) {
#pragma unroll
                for (int r = 0; r < 4; r++)
                    Ko[(size_t)(rowb + r) * 1024 + (col - 1024)] = f2bf(acc[i][j][r] + bvv);
            } else {
                int cc = col - 2048;
                int bb = rowb >> 11;
                int sp = ((m0 + wm * 64) & 2047) + (i >> 1) * 32 + l4 * 8 + (i & 1) * 4;
                int hh = cc >> 6, dd = cc & 63;
                ushort4 o;
                o.x = f2bf(acc[i][j][0] + bvv);
                o.y = f2bf(acc[i][j][1] + bvv);
                o.z = f2bf(acc[i][j][2] + bvv);
                o.w = f2bf(acc[i][j][3] + bvv);
                *(ushort4*)(Vo + ((size_t)((bb * 16 + hh) * 64 + dd)) * 2048 + sp) = o;
            }
        }
    }
}

// ---------------- output projection GEMM (R8-proven, fp32 out) ----------------
__global__ __launch_bounds__(256, 2) void gemm_o(
        const u16* __restrict__ A, const u16* __restrict__ W,
        const float* __restrict__ bias, float* __restrict__ out) {
    __shared__ __align__(16) u16 As[2][128 * 32];
    __shared__ __align__(16) u16 Bs[2][128 * 32];
    const int tid = threadIdx.x;
    const int lane = tid & 63;
    const int w = tid >> 6, wm = w >> 1, wn = w & 1;
    const int l15 = lane & 15, l4 = lane >> 4;
    int v = (blockIdx.x & 7) * 64 + (blockIdx.x >> 3);
    int vy = v >> 3, vx = v & 7;
    const int m0 = vy * 128, n0 = vx * 128;

    f32x4 acc[4][4];
#pragma unroll
    for (int i = 0; i < 4; i++)
#pragma unroll
        for (int j = 0; j < 4; j++) acc[i][j] = f32x4{0.f, 0.f, 0.f, 0.f};

#define O_STAGE(buf, kt) do {                                              \
    _Pragma("unroll")                                                      \
    for (int i_ = 0; i_ < 2; i_++) {                                       \
        int c_ = tid + i_ * 256;                                           \
        int row_ = c_ >> 2, slot_ = c_ & 3;                                \
        int cc_ = slot_ ^ ((row_ >> 1) & 3);                               \
        GLL16(A + (size_t)(m0 + row_) * 1024 + (kt) + cc_ * 8, As[buf] + c_ * 8); \
    }                                                                      \
    _Pragma("unroll")                                                      \
    for (int i_ = 0; i_ < 2; i_++) {                                       \
        int c_ = tid + i_ * 256;                                           \
        int row_ = c_ >> 2, slot_ = c_ & 3;                                \
        int cc_ = slot_ ^ ((row_ >> 1) & 3);                               \
        GLL16(W + (size_t)(n0 + row_) * 1024 + (kt) + cc_ * 8, Bs[buf] + c_ * 8); \
    }                                                                      \
} while (0)

    O_STAGE(0, 0);
    __syncthreads();

    for (int kt = 0; kt < 1024; kt += 32) {
        const int cur = (kt >> 5) & 1;
        if (kt != 992) O_STAGE(cur ^ 1, kt + 32);

        bf16x8 af[4], bfr[4];
#pragma unroll
        for (int i = 0; i < 4; i++) {
            int row = wm * 64 + i * 16 + l15;
            int slot = l4 ^ ((row >> 1) & 3);
            af[i] = *(const bf16x8*)(As[cur] + row * 32 + slot * 8);
        }
#pragma unroll
        for (int j = 0; j < 4; j++) {
            int row = wn * 64 + j * 16 + l15;
            int slot = l4 ^ ((row >> 1) & 3);
            bfr[j] = *(const bf16x8*)(Bs[cur] + row * 32 + slot * 8);
        }
#pragma unroll
        for (int i = 0; i < 4; i++)
#pragma unroll
            for (int j = 0; j < 4; j++)
                acc[i][j] = __builtin_amdgcn_mfma_f32_16x16x32_bf16(af[i], bfr[j], acc[i][j], 0, 0, 0);
        __syncthreads();
    }
#undef O_STAGE

#pragma unroll
    for (int j = 0; j < 4; j++) {
        int col = n0 + wn * 64 + j * 16 + l15;
        float bvv = bias[col];
#pragma unroll
        for (int i = 0; i < 4; i++) {
            int rowb = m0 + wm * 64 + i * 16 + l4 * 4;
#pragma unroll
            for (int r = 0; r < 4; r++)
                out[(size_t)(rowb + r) * 1024 + col] = acc[i][j][r] + bvv;
        }
    }
}

// ---------------- fused flash attention (R8 structure, KVBLK=128) ----------------
// 1D grid 1024, XCD swizzle (K/V L2-resident). 4 waves x 32 q-rows.
// KVBLK=128: each staged tile covers 128 KV rows (two 64-row halves computed
// sequentially, reusing the same registers) -> barrier count and per-iter
// fixed costs halved vs R8; 72 MFMA per barrier period. Sync pattern is
// EXACTLY R8's proven {STAGE(next) -> compute -> __syncthreads}.
// LDS 64 KB (2 blocks/CU = measured R8 occupancy, no loss).
__global__ __launch_bounds__(256, 3) void attn_fused(
        const u16* __restrict__ Q, const u16* __restrict__ K,
        const u16* __restrict__ Vt, const float* __restrict__ mask,
        u16* __restrict__ ctx) {
    __shared__ __align__(16) u16 Ks[2][128 * 64];   // [kv=128][d=64], swizzled slots
    __shared__ __align__(16) u16 Vs[2][64 * 128];   // [d=64][s'=128], swizzled slots

    const int tid = threadIdx.x, lane = tid & 63, w = tid >> 6;
    const int l15 = lane & 15, l4 = lane >> 4;
    const int bid = blockIdx.x;
    const int inner = bid >> 3;
    const int bh = ((inner >> 4) << 3) | (bid & 7);
    const int b = bh >> 4, h = bh & 15;
    const int qw = (inner & 15) * 128 + w * 32;
    const float THR2 = 8.0f;

    const u16* Qg = Q + (size_t)b * 2048 * 1024 + h * 64;
    const u16* Kg = K + (size_t)b * 2048 * 1024 + h * 64;
    const u16* Vg = Vt + (size_t)bh * 64 * 2048;
    const float* mp = mask + b * 2048;

    // ---- wave-redundant mask scan: 64 lanes x 8 float4 = 2048 ----
    bool anym;
    {
        bool bad = false;
#pragma unroll
        for (int i = 0; i < 8; i++) {
            float4 a = ((const float4*)mp)[lane * 8 + i];
            bad |= (a.x == 0.f) | (a.y == 0.f) | (a.z == 0.f) | (a.w == 0.f);
        }
        anym = (__ballot(bad) != 0ull);
    }

    // K: 1024 chunks (128 rows x 8), V: 1024 chunks (64 rows x 16). Swizzle
    // XORs only bits 0-2 of the chunk slot -> bit 3 (V's kv-half) unaffected,
    // so stage-source permutation == read permutation on both halves.
#define STAGE_KV(buf, kvbase) do {                                         \
    _Pragma("unroll")                                                      \
    for (int i_ = 0; i_ < 4; i_++) {                                       \
        int c_ = tid + i_ * 256;                                           \
        int row_ = c_ >> 3, slot_ = c_ & 7;                                \
        int cc_ = slot_ ^ (row_ & 7);                                      \
        GLL16(Kg + (size_t)((kvbase) + row_) * 1024 + cc_ * 8, Ks[buf] + c_ * 8); \
    }                                                                      \
    _Pragma("unroll")                                                      \
    for (int i_ = 0; i_ < 4; i_++) {                                       \
        int c_ = tid + i_ * 256;                                           \
        int row_ = c_ >> 4, slot_ = c_ & 15;                               \
        int cc_ = slot_ ^ (row_ & 7);                                      \
        GLL16(Vg + (size_t)row_ * 2048 + (kvbase) + cc_ * 8, Vs[buf] + c_ * 8); \
    }                                                                      \
} while (0)

    // hoist Q fragments (B-operand layout), already scaled by log2e/32
    bf16x8 qfr[2][2];
#pragma unroll
    for (int qi = 0; qi < 2; qi++)
#pragma unroll
        for (int kf = 0; kf < 2; kf++)
            qfr[qi][kf] = *(const bf16x8*)(Qg + (size_t)(qw + qi * 16 + l15) * 1024 + kf * 32 + l4 * 8);

    // q-mask 0/1 flag (cold path only)
    float mq01[2];
#pragma unroll
    for (int qi = 0; qi < 2; qi++)
        mq01[qi] = (mp[qw + qi * 16 + l15] != 0.f) ? 1.f : 0.f;

    float m_run[2] = {0.f, 0.f};
    f32x4 acc_l[2];      // denominator via ones-MFMA
    f32x4 oaccT[4][2];   // O^T: [d-frag][q-frag]
#pragma unroll
    for (int qi = 0; qi < 2; qi++) acc_l[qi] = f32x4{0.f, 0.f, 0.f, 0.f};
#pragma unroll
    for (int df = 0; df < 4; df++)
#pragma unroll
        for (int qi = 0; qi < 2; qi++) oaccT[df][qi] = f32x4{0.f, 0.f, 0.f, 0.f};

    const u32x4 ones4 = u32x4{0x3F803F80u, 0x3F803F80u, 0x3F803F80u, 0x3F803F80u};
    const bf16x8 ones = __builtin_bit_cast(bf16x8, ones4);

    STAGE_KV(0, 0);
    __syncthreads();

    for (int it = 0; it < 16; ++it) {
        const int cur = it & 1;

        if (it != 15) STAGE_KV(cur ^ 1, (it + 1) * 128);

#pragma unroll
        for (int hf = 0; hf < 2; hf++) {
            const int kv0 = it * 128 + hf * 64;

            // ---- S^T = K Q^T (emits base-2 scores; Q pre-scaled) ----
            bf16x8 kfr[4][2];
#pragma unroll
            for (int kvf = 0; kvf < 4; kvf++)
#pragma unroll
                for (int kf = 0; kf < 2; kf++) {
                    int row = hf * 64 + kvf * 16 + l15;
                    int slot = (kf * 4 + l4) ^ (row & 7);
                    kfr[kvf][kf] = *(const bf16x8*)(Ks[cur] + row * 64 + slot * 8);
                }
            f32x4 p[4][2];
#pragma unroll
            for (int kvf = 0; kvf < 4; kvf++)
#pragma unroll
                for (int qi = 0; qi < 2; qi++) p[kvf][qi] = f32x4{0.f, 0.f, 0.f, 0.f};
            __builtin_amdgcn_s_setprio(1);
#pragma unroll
            for (int kvf = 0; kvf < 4; kvf++)
#pragma unroll
                for (int qi = 0; qi < 2; qi++)
#pragma unroll
                    for (int kf = 0; kf < 2; kf++)
                        p[kvf][qi] = __builtin_amdgcn_mfma_f32_16x16x32_bf16(kfr[kvf][kf], qfr[qi][kf], p[kvf][qi], 0, 0, 0);
            __builtin_amdgcn_s_setprio(0);

            // ---- cold masked path: p = p*mq01 + kbias ----
            if (anym) {
                float4 mkv[4];
#pragma unroll
                for (int kvf = 0; kvf < 4; kvf++)
                    mkv[kvf] = ((const float4*)(mp + kv0))[kvf * 4 + l4];
#pragma unroll
                for (int qi = 0; qi < 2; qi++)
#pragma unroll
                    for (int kvf = 0; kvf < 4; kvf++)
#pragma unroll
                        for (int r = 0; r < 4; r++) {
                            float bb = (mkv[kvf][r] != 0.f) ? 0.f : -1e12f;
                            p[kvf][qi][r] = __builtin_fmaf(p[kvf][qi][r], mq01[qi], bb);
                        }
            }

            // ---- lane-local maxima; guard vs m_run + THR ----
            float t[2];
#pragma unroll
            for (int qi = 0; qi < 2; qi++) {
                float a0 = fmaxf(fmaxf(p[0][qi][0], p[0][qi][1]), fmaxf(p[0][qi][2], p[0][qi][3]));
                float a1 = fmaxf(fmaxf(p[1][qi][0], p[1][qi][1]), fmaxf(p[1][qi][2], p[1][qi][3]));
                float a2 = fmaxf(fmaxf(p[2][qi][0], p[2][qi][1]), fmaxf(p[2][qi][2], p[2][qi][3]));
                float a3 = fmaxf(fmaxf(p[3][qi][0], p[3][qi][1]), fmaxf(p[3][qi][2], p[3][qi][3]));
                t[qi] = fmaxf(fmaxf(a0, a1), fmaxf(a2, a3));
            }
            if (!__all((t[0] <= m_run[0] + THR2) && (t[1] <= m_run[1] + THR2))) {
                // cold rescale: cross-lane max, update m_run, scale accumulators
#pragma unroll
                for (int qi = 0; qi < 2; qi++) {
                    float tt = fmaxf(t[qi], __shfl_xor(t[qi], 16));
                    tt = fmaxf(tt, __shfl_xor(tt, 32));
                    float mn = fmaxf(m_run[qi], tt);
                    float sc = __builtin_amdgcn_exp2f(m_run[qi] - mn);
                    m_run[qi] = mn;
                    acc_l[qi] *= sc;
#pragma unroll
                    for (int df = 0; df < 4; df++) oaccT[df][qi] *= sc;
                }
            }
            // ---- exp2; m_run==0 fast path has no subtract ----
            if (__all((m_run[0] == 0.f) & (m_run[1] == 0.f))) {
#pragma unroll
                for (int qi = 0; qi < 2; qi++)
#pragma unroll
                    for (int kvf = 0; kvf < 4; kvf++)
#pragma unroll
                        for (int r = 0; r < 4; r++)
                            p[kvf][qi][r] = __builtin_amdgcn_exp2f(p[kvf][qi][r]);
            } else {
#pragma unroll
                for (int qi = 0; qi < 2; qi++)
#pragma unroll
                    for (int kvf = 0; kvf < 4; kvf++)
#pragma unroll
                        for (int r = 0; r < 4; r++)
                            p[kvf][qi][r] = __builtin_amdgcn_exp2f(p[kvf][qi][r] - m_run[qi]);
            }

            // ---- pb = lane-local P quads packed to bf16 ----
            bf16x8 pb[2][2];
#pragma unroll
            for (int qi = 0; qi < 2; qi++)
#pragma unroll
                for (int kf = 0; kf < 2; kf++) {
                    u32x4 tq;
                    tq.x = cvtpk(p[2 * kf][qi][0], p[2 * kf][qi][1]);
                    tq.y = cvtpk(p[2 * kf][qi][2], p[2 * kf][qi][3]);
                    tq.z = cvtpk(p[2 * kf + 1][qi][0], p[2 * kf + 1][qi][1]);
                    tq.w = cvtpk(p[2 * kf + 1][qi][2], p[2 * kf + 1][qi][3]);
                    pb[qi][kf] = __builtin_bit_cast(bf16x8, tq);
                }

            // V fragments after softmax (kept out of the VALU-phase live set)
            // chunk s8 = hf*8 + kf*4 + l4; slot = s8 ^ (row&7) (bit 3 = hf intact)
            bf16x8 vfr[4][2];
#pragma unroll
            for (int df = 0; df < 4; df++)
#pragma unroll
                for (int kf = 0; kf < 2; kf++) {
                    int row = df * 16 + l15;
                    int s8 = hf * 8 + kf * 4 + l4;
                    int slot = s8 ^ (row & 7);
                    vfr[df][kf] = *(const bf16x8*)(Vs[cur] + row * 128 + slot * 8);
                }

            // ---- O^T += V^T P^T ; l += ones^T P^T ----
            __builtin_amdgcn_s_setprio(1);
#pragma unroll
            for (int df = 0; df < 4; df++)
#pragma unroll
                for (int qi = 0; qi < 2; qi++)
#pragma unroll
                    for (int kf = 0; kf < 2; kf++)
                        oaccT[df][qi] = __builtin_amdgcn_mfma_f32_16x16x32_bf16(vfr[df][kf], pb[qi][kf], oaccT[df][qi], 0, 0, 0);
#pragma unroll
            for (int qi = 0; qi < 2; qi++)
#pragma unroll
                for (int kf = 0; kf < 2; kf++)
                    acc_l[qi] = __builtin_amdgcn_mfma_f32_16x16x32_bf16(ones, pb[qi][kf], acc_l[qi], 0, 0, 0);
            __builtin_amdgcn_s_setprio(0);
        }

        __syncthreads();   // drains prefetch vmcnt + protects both dbuf halves
    }

    // ---- epilogue: ctx[token][h*64+d] = O^T / l ----
#pragma unroll
    for (int qi = 0; qi < 2; qi++) {
        float rl = 1.0f / acc_l[qi][0];
        int tok = qw + qi * 16 + l15;
#pragma unroll
        for (int df = 0; df < 4; df++) {
            uint2 o;
            o.x = cvtpk(oaccT[df][qi][0] * rl, oaccT[df][qi][1] * rl);
            o.y = cvtpk(oaccT[df][qi][2] * rl, oaccT[df][qi][3] * rl);
            *(uint2*)(ctx + (size_t)(b * 2048 + tok) * 1024 + h * 64 + df * 16 + l4 * 4) = o;
        }
    }
#undef STAGE_KV
}

extern "C" void kernel_launch(void* const* d_in, const int* in_sizes, int n_in,
                              void* d_out, int out_size, void* d_ws, size_t ws_size,
                              hipStream_t stream) {
    const float* hs    = (const float*)d_in[0];
    const float* masks = (const float*)d_in[1];
    const float* Wq = (const float*)d_in[2];
    const float* bq = (const float*)d_in[3];
    const float* Wk = (const float*)d_in[4];
    const float* bk = (const float*)d_in[5];
    const float* Wv = (const float*)d_in[6];
    const float* bv = (const float*)d_in[7];
    const float* Wo = (const float*)d_in[8];
    const float* bo = (const float*)d_in[9];

    const int NT = 4 * 2048;   // 8192 tokens
    const int H = 1024;

    u16* hs_b = (u16*)d_ws;                       // [8192,1024]
    u16* w_b  = hs_b + (size_t)NT * H;            // [Wq|Wk|Wv|Wo] 4x[1024,1024]
    u16* wo_b = w_b + (size_t)3 * H * H;
    u16* Qb   = w_b + (size_t)4 * H * H;          // [8192,1024] (pre-scaled)
    u16* Kb   = Qb + (size_t)NT * H;              // [8192,1024]
    u16* Vtb  = Kb + (size_t)NT * H;              // [64][64][2048] s'-permuted
    u16* Cb   = hs_b;                             // attn output reuses hidden buffer

    cvt_f32_bf16<<<NT * H / 1024, 256, 0, stream>>>(hs, hs_b, NT * H / 4);
    cvt_w4<<<dim3(H * H / 1024, 4), 256, 0, stream>>>(Wq, Wk, Wv, Wo, w_b);

    gemm_qkv<<<1536, 256, 0, stream>>>(hs_b, w_b, bq, bk, bv, Qb, Kb, Vtb);

    attn_fused<<<1024, 256, 0, stream>>>(Qb, Kb, Vtb, masks, Cb);

    gemm_o<<<512, 256, 0, stream>>>(Cb, wo_b, bo, (float*)d_out);
}

// Round 14
// 201.650 us; speedup vs baseline: 1.0768x; 1.0072x over previous
//
#include <hip/hip_runtime.h>
#include <hip/hip_bf16.h>
#include <stdint.h>

typedef unsigned short u16;
typedef __attribute__((ext_vector_type(4))) float f32x4;
typedef __attribute__((ext_vector_type(8))) short bf16x8;
typedef __attribute__((ext_vector_type(4))) unsigned int u32x4;

#define GLL16(src, dst) __builtin_amdgcn_global_load_lds( \
    (const __attribute__((address_space(1))) void*)(src), \
    (__attribute__((address_space(3))) void*)(dst), 16, 0, 0)

static __device__ __forceinline__ u16 f2bf(float x) {
    uint32_t u = __builtin_bit_cast(uint32_t, x);
    u += 0x7fffu + ((u >> 16) & 1u);
    return (u16)(u >> 16);
}

static __device__ __forceinline__ uint32_t cvtpk(float lo, float hi) {
    uint32_t r;
    asm("v_cvt_pk_bf16_f32 %0, %1, %2" : "=v"(r) : "v"(lo), "v"(hi));
    return r;
}

// ---------------- fused fp32 -> bf16 conversion: hs + all 4 weights ----------------
// dst is contiguous in ws: [hs_b (8192x1024) | Wq | Wk | Wv | Wo (1024x1024 each)].
// 12288 blocks x 1024 elems; one dispatch replaces the former two.
__global__ __launch_bounds__(256) void cvt_all(
        const float* __restrict__ hs, const float* __restrict__ w0,
        const float* __restrict__ w1, const float* __restrict__ w2,
        const float* __restrict__ w3, u16* __restrict__ dst) {
    int blk = blockIdx.x;
    const float* src;
    if (blk < 8192) {
        src = hs + (size_t)blk * 1024;
    } else {
        int j = blk - 8192;
        int wsel = j >> 10;
        const float* w = (wsel == 0) ? w0 : (wsel == 1) ? w1 : (wsel == 2) ? w2 : w3;
        src = w + (size_t)(j & 1023) * 1024;
    }
    int i = threadIdx.x;
    float4 v = ((const float4*)src)[i];
    ushort4 o;
    o.x = f2bf(v.x); o.y = f2bf(v.y); o.z = f2bf(v.z); o.w = f2bf(v.w);
    ((ushort4*)(dst + (size_t)blk * 1024))[i] = o;
}

// ---------------- fused QKV GEMM (R8-proven) ----------------
__global__ __launch_bounds__(256, 2) void gemm_qkv(
        const u16* __restrict__ A, const u16* __restrict__ W,
        const float* __restrict__ bq, const float* __restrict__ bk,
        const float* __restrict__ bv,
        u16* __restrict__ Qo, u16* __restrict__ Ko, u16* __restrict__ Vo) {
    __shared__ __align__(16) u16 As[2][128 * 32];
    __shared__ __align__(16) u16 Bs[2][128 * 32];
    const int tid = threadIdx.x;
    const int lane = tid & 63;
    const int w = tid >> 6, wm = w >> 1, wn = w & 1;
    const int l15 = lane & 15, l4 = lane >> 4;
    int v = (blockIdx.x & 7) * 192 + (blockIdx.x >> 3);
    int vy = v / 24, vx = v - vy * 24;
    const int m0 = vy * 128, n0 = vx * 128;
    const float SC2 = 0.03125f * 1.44269504088896f;

    f32x4 acc[4][4];
#pragma unroll
    for (int i = 0; i < 4; i++)
#pragma unroll
        for (int j = 0; j < 4; j++) acc[i][j] = f32x4{0.f, 0.f, 0.f, 0.f};

#define QKV_STAGE(buf, kt) do {                                            \
    _Pragma("unroll")                                                      \
    for (int i_ = 0; i_ < 2; i_++) {                                       \
        int c_ = tid + i_ * 256;                                           \
        int row_ = c_ >> 2, slot_ = c_ & 3;                                \
        int cc_ = slot_ ^ ((row_ >> 1) & 3);                               \
        GLL16(A + (size_t)(m0 + row_) * 1024 + (kt) + cc_ * 8, As[buf] + c_ * 8); \
    }                                                                      \
    _Pragma("unroll")                                                      \
    for (int i_ = 0; i_ < 2; i_++) {                                       \
        int c_ = tid + i_ * 256;                                           \
        int row_ = c_ >> 2, slot_ = c_ & 3;                                \
        int cc_ = slot_ ^ ((row_ >> 1) & 3);                               \
        GLL16(W + (size_t)(n0 + row_) * 1024 + (kt) + cc_ * 8, Bs[buf] + c_ * 8); \
    }                                                                      \
} while (0)

    QKV_STAGE(0, 0);
    __syncthreads();

    for (int kt = 0; kt < 1024; kt += 32) {
        const int cur = (kt >> 5) & 1;
        if (kt != 992) QKV_STAGE(cur ^ 1, kt + 32);

        bf16x8 af[4], bfr[4];
#pragma unroll
        for (int i = 0; i < 4; i++) {
            int row = wm * 64 + i * 16 + l15;
            int slot = l4 ^ ((row >> 1) & 3);
            af[i] = *(const bf16x8*)(As[cur] + row * 32 + slot * 8);
        }
#pragma unroll
        for (int j = 0; j < 4; j++) {
            int row = wn * 64 + j * 16 + l15;
            int slot = l4 ^ ((row >> 1) & 3);
            bfr[j] = *(const bf16x8*)(Bs[cur] + row * 32 + slot * 8);
        }
#pragma unroll
        for (int i = 0; i < 4; i++)
#pragma unroll
            for (int j = 0; j < 4; j++)
                acc[i][j] = __builtin_amdgcn_mfma_f32_16x16x32_bf16(af[i], bfr[j], acc[i][j], 0, 0, 0);
        __syncthreads();
    }
#undef QKV_STAGE

#pragma unroll
    for (int j = 0; j < 4; j++) {
        int col = n0 + wn * 64 + j * 16 + l15;
        int sel = col >> 10;
        float bvv = (sel == 0) ? bq[col] : (sel == 1) ? bk[col - 1024] : bv[col - 2048];
#pragma unroll
        for (int i = 0; i < 4; i++) {
            int rowb = m0 + wm * 64 + i * 16 + l4 * 4;
            if (sel == 0) {
#pragma unroll
                for (int r = 0; r < 4; r++)
                    Qo[(size_t)(rowb + r) * 1024 + col] = f2bf((acc[i][j][r] + bvv) * SC2);
            } else if (sel == 1) {
#pragma unroll
                for (int r = 0; r < 4; r++)
                    Ko[(size_t)(rowb + r) * 1024 + (col - 1024)] = f2bf(acc[i][j][r] + bvv);
            } else {
                int cc = col - 2048;
                int bb = rowb >> 11;
                int sp = ((m0 + wm * 64) & 2047) + (i >> 1) * 32 + l4 * 8 + (i & 1) * 4;
                int hh = cc >> 6, dd = cc & 63;
                ushort4 o;
                o.x = f2bf(acc[i][j][0] + bvv);
                o.y = f2bf(acc[i][j][1] + bvv);
                o.z = f2bf(acc[i][j][2] + bvv);
                o.w = f2bf(acc[i][j][3] + bvv);
                *(ushort4*)(Vo + ((size_t)((bb * 16 + hh) * 64 + dd)) * 2048 + sp) = o;
            }
        }
    }
}

// ---------------- output projection GEMM (R8-proven, fp32 out) ----------------
__global__ __launch_bounds__(256, 2) void gemm_o(
        const u16* __restrict__ A, const u16* __restrict__ W,
        const float* __restrict__ bias, float* __restrict__ out) {
    __shared__ __align__(16) u16 As[2][128 * 32];
    __shared__ __align__(16) u16 Bs[2][128 * 32];
    const int tid = threadIdx.x;
    const int lane = tid & 63;
    const int w = tid >> 6, wm = w >> 1, wn = w & 1;
    const int l15 = lane & 15, l4 = lane >> 4;
    int v = (blockIdx.x & 7) * 64 + (blockIdx.x >> 3);
    int vy = v >> 3, vx = v & 7;
    const int m0 = vy * 128, n0 = vx * 128;

    f32x4 acc[4][4];
#pragma unroll
    for (int i = 0; i < 4; i++)
#pragma unroll
        for (int j = 0; j < 4; j++) acc[i][j] = f32x4{0.f, 0.f, 0.f, 0.f};

#define O_STAGE(buf, kt) do {                                              \
    _Pragma("unroll")                                                      \
    for (int i_ = 0; i_ < 2; i_++) {                                       \
        int c_ = tid + i_ * 256;                                           \
        int row_ = c_ >> 2, slot_ = c_ & 3;                                \
        int cc_ = slot_ ^ ((row_ >> 1) & 3);                               \
        GLL16(A + (size_t)(m0 + row_) * 1024 + (kt) + cc_ * 8, As[buf] + c_ * 8); \
    }                                                                      \
    _Pragma("unroll")                                                      \
    for (int i_ = 0; i_ < 2; i_++) {                                       \
        int c_ = tid + i_ * 256;                                           \
        int row_ = c_ >> 2, slot_ = c_ & 3;                                \
        int cc_ = slot_ ^ ((row_ >> 1) & 3);                               \
        GLL16(W + (size_t)(n0 + row_) * 1024 + (kt) + cc_ * 8, Bs[buf] + c_ * 8); \
    }                                                                      \
} while (0)

    O_STAGE(0, 0);
    __syncthreads();

    for (int kt = 0; kt < 1024; kt += 32) {
        const int cur = (kt >> 5) & 1;
        if (kt != 992) O_STAGE(cur ^ 1, kt + 32);

        bf16x8 af[4], bfr[4];
#pragma unroll
        for (int i = 0; i < 4; i++) {
            int row = wm * 64 + i * 16 + l15;
            int slot = l4 ^ ((row >> 1) & 3);
            af[i] = *(const bf16x8*)(As[cur] + row * 32 + slot * 8);
        }
#pragma unroll
        for (int j = 0; j < 4; j++) {
            int row = wn * 64 + j * 16 + l15;
            int slot = l4 ^ ((row >> 1) & 3);
            bfr[j] = *(const bf16x8*)(Bs[cur] + row * 32 + slot * 8);
        }
#pragma unroll
        for (int i = 0; i < 4; i++)
#pragma unroll
            for (int j = 0; j < 4; j++)
                acc[i][j] = __builtin_amdgcn_mfma_f32_16x16x32_bf16(af[i], bfr[j], acc[i][j], 0, 0, 0);
        __syncthreads();
    }
#undef O_STAGE

#pragma unroll
    for (int j = 0; j < 4; j++) {
        int col = n0 + wn * 64 + j * 16 + l15;
        float bvv = bias[col];
#pragma unroll
        for (int i = 0; i < 4; i++) {
            int rowb = m0 + wm * 64 + i * 16 + l4 * 4;
#pragma unroll
            for (int r = 0; r < 4; r++)
                out[(size_t)(rowb + r) * 1024 + col] = acc[i][j][r] + bvv;
        }
    }
}

// ---------------- fused flash attention (R8 structure + isolated vfr-hoist) ----------------
// 1D grid 1024, XCD swizzle (K/V L2-resident). 4 waves x 32 q-rows, KVBLK=64.
// Exactly R8's proven {STAGE(next) -> compute -> __syncthreads} loop; the ONE
// change vs R8: vfr ds_reads moved directly after QK^T so their latency hides
// under the softmax VALU phase (R9 bundled this with hand-vmcnt and regressed;
// this isolates the hoist). Live set ~112 VGPR < the (256,3)/170 cap.
__global__ __launch_bounds__(256, 3) void attn_fused(
        const u16* __restrict__ Q, const u16* __restrict__ K,
        const u16* __restrict__ Vt, const float* __restrict__ mask,
        u16* __restrict__ ctx) {
    __shared__ __align__(16) u16 Ks[2][64 * 64];    // [kv][d], swizzled slots
    __shared__ __align__(16) u16 Vs[2][64 * 64];    // [d][s'], swizzled slots

    const int tid = threadIdx.x, lane = tid & 63, w = tid >> 6;
    const int l15 = lane & 15, l4 = lane >> 4;
    const int bid = blockIdx.x;
    const int inner = bid >> 3;
    const int bh = ((inner >> 4) << 3) | (bid & 7);
    const int b = bh >> 4, h = bh & 15;
    const int qw = (inner & 15) * 128 + w * 32;
    const float THR2 = 8.0f;

    const u16* Qg = Q + (size_t)b * 2048 * 1024 + h * 64;
    const u16* Kg = K + (size_t)b * 2048 * 1024 + h * 64;
    const u16* Vg = Vt + (size_t)bh * 64 * 2048;
    const float* mp = mask + b * 2048;

    // ---- wave-redundant mask scan: 64 lanes x 8 float4 = 2048 ----
    bool anym;
    {
        bool bad = false;
#pragma unroll
        for (int i = 0; i < 8; i++) {
            float4 a = ((const float4*)mp)[lane * 8 + i];
            bad |= (a.x == 0.f) | (a.y == 0.f) | (a.z == 0.f) | (a.w == 0.f);
        }
        anym = (__ballot(bad) != 0ull);
    }

#define STAGE_KV(buf, kvbase) do {                                         \
    _Pragma("unroll")                                                      \
    for (int i_ = 0; i_ < 2; i_++) {                                       \
        int c_ = tid + i_ * 256;                                           \
        int row_ = c_ >> 3, slot_ = c_ & 7;                                \
        int cc_ = slot_ ^ (row_ & 7);                                      \
        GLL16(Kg + (size_t)((kvbase) + row_) * 1024 + cc_ * 8, Ks[buf] + c_ * 8); \
    }                                                                      \
    _Pragma("unroll")                                                      \
    for (int i_ = 0; i_ < 2; i_++) {                                       \
        int c_ = tid + i_ * 256;                                           \
        int row_ = c_ >> 3, slot_ = c_ & 7;                                \
        int cc_ = slot_ ^ (row_ & 7);                                      \
        GLL16(Vg + (size_t)row_ * 2048 + (kvbase) + cc_ * 8, Vs[buf] + c_ * 8); \
    }                                                                      \
} while (0)

    // hoist Q fragments (B-operand layout), already scaled by log2e/32
    bf16x8 qfr[2][2];
#pragma unroll
    for (int qi = 0; qi < 2; qi++)
#pragma unroll
        for (int kf = 0; kf < 2; kf++)
            qfr[qi][kf] = *(const bf16x8*)(Qg + (size_t)(qw + qi * 16 + l15) * 1024 + kf * 32 + l4 * 8);

    // q-mask 0/1 flag (cold path only)
    float mq01[2];
#pragma unroll
    for (int qi = 0; qi < 2; qi++)
        mq01[qi] = (mp[qw + qi * 16 + l15] != 0.f) ? 1.f : 0.f;

    float m_run[2] = {0.f, 0.f};
    f32x4 acc_l[2];      // denominator via ones-MFMA
    f32x4 oaccT[4][2];   // O^T: [d-frag][q-frag]
#pragma unroll
    for (int qi = 0; qi < 2; qi++) acc_l[qi] = f32x4{0.f, 0.f, 0.f, 0.f};
#pragma unroll
    for (int df = 0; df < 4; df++)
#pragma unroll
        for (int qi = 0; qi < 2; qi++) oaccT[df][qi] = f32x4{0.f, 0.f, 0.f, 0.f};

    const u32x4 ones4 = u32x4{0x3F803F80u, 0x3F803F80u, 0x3F803F80u, 0x3F803F80u};
    const bf16x8 ones = __builtin_bit_cast(bf16x8, ones4);

    STAGE_KV(0, 0);
    __syncthreads();

    for (int it = 0; it < 32; ++it) {
        const int cur = it & 1;
        const int kv0 = it * 64;

        if (it != 31) STAGE_KV(cur ^ 1, kv0 + 64);

        // ---- S^T = K Q^T (emits base-2 scores; Q pre-scaled) ----
        bf16x8 kfr[4][2];
#pragma unroll
        for (int kvf = 0; kvf < 4; kvf++)
#pragma unroll
            for (int kf = 0; kf < 2; kf++) {
                int row = kvf * 16 + l15;
                int slot = (kf * 4 + l4) ^ (row & 7);
                kfr[kvf][kf] = *(const bf16x8*)(Ks[cur] + row * 64 + slot * 8);
            }
        f32x4 p[4][2];
#pragma unroll
        for (int kvf = 0; kvf < 4; kvf++)
#pragma unroll
            for (int qi = 0; qi < 2; qi++) p[kvf][qi] = f32x4{0.f, 0.f, 0.f, 0.f};
        __builtin_amdgcn_s_setprio(1);
#pragma unroll
        for (int kvf = 0; kvf < 4; kvf++)
#pragma unroll
            for (int qi = 0; qi < 2; qi++)
#pragma unroll
                for (int kf = 0; kf < 2; kf++)
                    p[kvf][qi] = __builtin_amdgcn_mfma_f32_16x16x32_bf16(kfr[kvf][kf], qfr[qi][kf], p[kvf][qi], 0, 0, 0);
        __builtin_amdgcn_s_setprio(0);

        // ---- vfr issued HERE (the isolated change vs R8): ds_read latency
        //      overlaps the softmax VALU phase below ----
        bf16x8 vfr[4][2];
#pragma unroll
        for (int df = 0; df < 4; df++)
#pragma unroll
            for (int kf = 0; kf < 2; kf++) {
                int row = df * 16 + l15;
                int slot = (kf * 4 + l4) ^ (row & 7);
                vfr[df][kf] = *(const bf16x8*)(Vs[cur] + row * 64 + slot * 8);
            }

        // ---- cold masked path: p = p*mq01 + kbias ----
        if (anym) {
            float4 mkv[4];
#pragma unroll
            for (int kvf = 0; kvf < 4; kvf++)
                mkv[kvf] = ((const float4*)(mp + kv0))[kvf * 4 + l4];
#pragma unroll
            for (int qi = 0; qi < 2; qi++)
#pragma unroll
                for (int kvf = 0; kvf < 4; kvf++)
#pragma unroll
                    for (int r = 0; r < 4; r++) {
                        float bb = (mkv[kvf][r] != 0.f) ? 0.f : -1e12f;
                        p[kvf][qi][r] = __builtin_fmaf(p[kvf][qi][r], mq01[qi], bb);
                    }
        }

        // ---- lane-local maxima; guard vs m_run + THR ----
        float t[2];
#pragma unroll
        for (int qi = 0; qi < 2; qi++) {
            float a0 = fmaxf(fmaxf(p[0][qi][0], p[0][qi][1]), fmaxf(p[0][qi][2], p[0][qi][3]));
            float a1 = fmaxf(fmaxf(p[1][qi][0], p[1][qi][1]), fmaxf(p[1][qi][2], p[1][qi][3]));
            float a2 = fmaxf(fmaxf(p[2][qi][0], p[2][qi][1]), fmaxf(p[2][qi][2], p[2][qi][3]));
            float a3 = fmaxf(fmaxf(p[3][qi][0], p[3][qi][1]), fmaxf(p[3][qi][2], p[3][qi][3]));
            t[qi] = fmaxf(fmaxf(a0, a1), fmaxf(a2, a3));
        }
        if (!__all((t[0] <= m_run[0] + THR2) && (t[1] <= m_run[1] + THR2))) {
            // cold rescale: cross-lane max, update m_run, scale accumulators
#pragma unroll
            for (int qi = 0; qi < 2; qi++) {
                float tt = fmaxf(t[qi], __shfl_xor(t[qi], 16));
                tt = fmaxf(tt, __shfl_xor(tt, 32));
                float mn = fmaxf(m_run[qi], tt);
                float sc = __builtin_amdgcn_exp2f(m_run[qi] - mn);
                m_run[qi] = mn;
                acc_l[qi] *= sc;
#pragma unroll
                for (int df = 0; df < 4; df++) oaccT[df][qi] *= sc;
            }
        }
        // ---- exp2; m_run==0 fast path has no subtract ----
        if (__all((m_run[0] == 0.f) & (m_run[1] == 0.f))) {
#pragma unroll
            for (int qi = 0; qi < 2; qi++)
#pragma unroll
                for (int kvf = 0; kvf < 4; kvf++)
#pragma unroll
                    for (int r = 0; r < 4; r++)
                        p[kvf][qi][r] = __builtin_amdgcn_exp2f(p[kvf][qi][r]);
        } else {
#pragma unroll
            for (int qi = 0; qi < 2; qi++)
#pragma unroll
                for (int kvf = 0; kvf < 4; kvf++)
#pragma unroll
                    for (int r = 0; r < 4; r++)
                        p[kvf][qi][r] = __builtin_amdgcn_exp2f(p[kvf][qi][r] - m_run[qi]);
        }

        // ---- pb = lane-local P quads packed to bf16 ----
        bf16x8 pb[2][2];
#pragma unroll
        for (int qi = 0; qi < 2; qi++)
#pragma unroll
            for (int kf = 0; kf < 2; kf++) {
                u32x4 tq;
                tq.x = cvtpk(p[2 * kf][qi][0], p[2 * kf][qi][1]);
                tq.y = cvtpk(p[2 * kf][qi][2], p[2 * kf][qi][3]);
                tq.z = cvtpk(p[2 * kf + 1][qi][0], p[2 * kf + 1][qi][1]);
                tq.w = cvtpk(p[2 * kf + 1][qi][2], p[2 * kf + 1][qi][3]);
                pb[qi][kf] = __builtin_bit_cast(bf16x8, tq);
            }

        // ---- O^T += V^T P^T ; l += ones^T P^T ----
        __builtin_amdgcn_s_setprio(1);
#pragma unroll
        for (int df = 0; df < 4; df++)
#pragma unroll
            for (int qi = 0; qi < 2; qi++)
#pragma unroll
                for (int kf = 0; kf < 2; kf++)
                    oaccT[df][qi] = __builtin_amdgcn_mfma_f32_16x16x32_bf16(vfr[df][kf], pb[qi][kf], oaccT[df][qi], 0, 0, 0);
#pragma unroll
        for (int qi = 0; qi < 2; qi++)
#pragma unroll
            for (int kf = 0; kf < 2; kf++)
                acc_l[qi] = __builtin_amdgcn_mfma_f32_16x16x32_bf16(ones, pb[qi][kf], acc_l[qi], 0, 0, 0);
        __builtin_amdgcn_s_setprio(0);

        __syncthreads();   // drains prefetch vmcnt + protects both dbuf halves
    }

    // ---- epilogue: ctx[token][h*64+d] = O^T / l ----
#pragma unroll
    for (int qi = 0; qi < 2; qi++) {
        float rl = 1.0f / acc_l[qi][0];
        int tok = qw + qi * 16 + l15;
#pragma unroll
        for (int df = 0; df < 4; df++) {
            uint2 o;
            o.x = cvtpk(oaccT[df][qi][0] * rl, oaccT[df][qi][1] * rl);
            o.y = cvtpk(oaccT[df][qi][2] * rl, oaccT[df][qi][3] * rl);
            *(uint2*)(ctx + (size_t)(b * 2048 + tok) * 1024 + h * 64 + df * 16 + l4 * 4) = o;
        }
    }
#undef STAGE_KV
}

extern "C" void kernel_launch(void* const* d_in, const int* in_sizes, int n_in,
                              void* d_out, int out_size, void* d_ws, size_t ws_size,
                              hipStream_t stream) {
    const float* hs    = (const float*)d_in[0];
    const float* masks = (const float*)d_in[1];
    const float* Wq = (const float*)d_in[2];
    const float* bq = (const float*)d_in[3];
    const float* Wk = (const float*)d_in[4];
    const float* bk = (const float*)d_in[5];
    const float* Wv = (const float*)d_in[6];
    const float* bv = (const float*)d_in[7];
    const float* Wo = (const float*)d_in[8];
    const float* bo = (const float*)d_in[9];

    const int NT = 4 * 2048;   // 8192 tokens
    const int H = 1024;

    u16* hs_b = (u16*)d_ws;                       // [8192,1024]
    u16* w_b  = hs_b + (size_t)NT * H;            // [Wq|Wk|Wv|Wo] 4x[1024,1024]
    u16* wo_b = w_b + (size_t)3 * H * H;
    u16* Qb   = w_b + (size_t)4 * H * H;          // [8192,1024] (pre-scaled)
    u16* Kb   = Qb + (size_t)NT * H;              // [8192,1024]
    u16* Vtb  = Kb + (size_t)NT * H;              // [64][64][2048] s'-permuted
    u16* Cb   = hs_b;                             // attn output reuses hidden buffer

    // one fused conversion dispatch: hs + 4 weights into contiguous ws region
    cvt_all<<<12288, 256, 0, stream>>>(hs, Wq, Wk, Wv, Wo, hs_b);

    gemm_qkv<<<1536, 256, 0, stream>>>(hs_b, w_b, bq, bk, bv, Qb, Kb, Vtb);

    attn_fused<<<1024, 256, 0, stream>>>(Qb, Kb, Vtb, masks, Cb);

    gemm_o<<<512, 256, 0, stream>>>(Cb, wo_b, bo, (float*)d_out);
}

// Round 15
// 201.247 us; speedup vs baseline: 1.0789x; 1.0020x over previous
//
#include <hip/hip_runtime.h>
#include <hip/hip_bf16.h>
#include <stdint.h>

typedef unsigned short u16;
typedef __attribute__((ext_vector_type(4))) float f32x4;
typedef __attribute__((ext_vector_type(8))) short bf16x8;
typedef __attribute__((ext_vector_type(4))) unsigned int u32x4;

#define GLL16(src, dst) __builtin_amdgcn_global_load_lds( \
    (const __attribute__((address_space(1))) void*)(src), \
    (__attribute__((address_space(3))) void*)(dst), 16, 0, 0)

static __device__ __forceinline__ u16 f2bf(float x) {
    uint32_t u = __builtin_bit_cast(uint32_t, x);
    u += 0x7fffu + ((u >> 16) & 1u);
    return (u16)(u >> 16);
}

static __device__ __forceinline__ uint32_t cvtpk(float lo, float hi) {
    uint32_t r;
    asm("v_cvt_pk_bf16_f32 %0, %1, %2" : "=v"(r) : "v"(lo), "v"(hi));
    return r;
}

// ---------------- fused fp32 -> bf16 conversion: hs + all 4 weights ----------------
// dst contiguous in ws: [hs_b (8192x1024) | Wq | Wk | Wv | Wo]. One dispatch.
__global__ __launch_bounds__(256) void cvt_all(
        const float* __restrict__ hs, const float* __restrict__ w0,
        const float* __restrict__ w1, const float* __restrict__ w2,
        const float* __restrict__ w3, u16* __restrict__ dst) {
    int blk = blockIdx.x;
    const float* src;
    if (blk < 8192) {
        src = hs + (size_t)blk * 1024;
    } else {
        int j = blk - 8192;
        int wsel = j >> 10;
        const float* w = (wsel == 0) ? w0 : (wsel == 1) ? w1 : (wsel == 2) ? w2 : w3;
        src = w + (size_t)(j & 1023) * 1024;
    }
    int i = threadIdx.x;
    float4 v = ((const float4*)src)[i];
    ushort4 o;
    o.x = f2bf(v.x); o.y = f2bf(v.y); o.z = f2bf(v.z); o.w = f2bf(v.w);
    ((ushort4*)(dst + (size_t)blk * 1024))[i] = o;
}

// ---------------- fused QKV GEMM (R8-proven) ----------------
__global__ __launch_bounds__(256, 2) void gemm_qkv(
        const u16* __restrict__ A, const u16* __restrict__ W,
        const float* __restrict__ bq, const float* __restrict__ bk,
        const float* __restrict__ bv,
        u16* __restrict__ Qo, u16* __restrict__ Ko, u16* __restrict__ Vo) {
    __shared__ __align__(16) u16 As[2][128 * 32];
    __shared__ __align__(16) u16 Bs[2][128 * 32];
    const int tid = threadIdx.x;
    const int lane = tid & 63;
    const int w = tid >> 6, wm = w >> 1, wn = w & 1;
    const int l15 = lane & 15, l4 = lane >> 4;
    int v = (blockIdx.x & 7) * 192 + (blockIdx.x >> 3);
    int vy = v / 24, vx = v - vy * 24;
    const int m0 = vy * 128, n0 = vx * 128;
    const float SC2 = 0.03125f * 1.44269504088896f;

    f32x4 acc[4][4];
#pragma unroll
    for (int i = 0; i < 4; i++)
#pragma unroll
        for (int j = 0; j < 4; j++) acc[i][j] = f32x4{0.f, 0.f, 0.f, 0.f};

#define QKV_STAGE(buf, kt) do {                                            \
    _Pragma("unroll")                                                      \
    for (int i_ = 0; i_ < 2; i_++) {                                       \
        int c_ = tid + i_ * 256;                                           \
        int row_ = c_ >> 2, slot_ = c_ & 3;                                \
        int cc_ = slot_ ^ ((row_ >> 1) & 3);                               \
        GLL16(A + (size_t)(m0 + row_) * 1024 + (kt) + cc_ * 8, As[buf] + c_ * 8); \
    }                                                                      \
    _Pragma("unroll")                                                      \
    for (int i_ = 0; i_ < 2; i_++) {                                       \
        int c_ = tid + i_ * 256;                                           \
        int row_ = c_ >> 2, slot_ = c_ & 3;                                \
        int cc_ = slot_ ^ ((row_ >> 1) & 3);                               \
        GLL16(W + (size_t)(n0 + row_) * 1024 + (kt) + cc_ * 8, Bs[buf] + c_ * 8); \
    }                                                                      \
} while (0)

    QKV_STAGE(0, 0);
    __syncthreads();

    for (int kt = 0; kt < 1024; kt += 32) {
        const int cur = (kt >> 5) & 1;
        if (kt != 992) QKV_STAGE(cur ^ 1, kt + 32);

        bf16x8 af[4], bfr[4];
#pragma unroll
        for (int i = 0; i < 4; i++) {
            int row = wm * 64 + i * 16 + l15;
            int slot = l4 ^ ((row >> 1) & 3);
            af[i] = *(const bf16x8*)(As[cur] + row * 32 + slot * 8);
        }
#pragma unroll
        for (int j = 0; j < 4; j++) {
            int row = wn * 64 + j * 16 + l15;
            int slot = l4 ^ ((row >> 1) & 3);
            bfr[j] = *(const bf16x8*)(Bs[cur] + row * 32 + slot * 8);
        }
#pragma unroll
        for (int i = 0; i < 4; i++)
#pragma unroll
            for (int j = 0; j < 4; j++)
                acc[i][j] = __builtin_amdgcn_mfma_f32_16x16x32_bf16(af[i], bfr[j], acc[i][j], 0, 0, 0);
        __syncthreads();
    }
#undef QKV_STAGE

#pragma unroll
    for (int j = 0; j < 4; j++) {
        int col = n0 + wn * 64 + j * 16 + l15;
        int sel = col >> 10;
        float bvv = (sel == 0) ? bq[col] : (sel == 1) ? bk[col - 1024] : bv[col - 2048];
#pragma unroll
        for (int i = 0; i < 4; i++) {
            int rowb = m0 + wm * 64 + i * 16 + l4 * 4;
            if (sel == 0) {
#pragma unroll
                for (int r = 0; r < 4; r++)
                    Qo[(size_t)(rowb + r) * 1024 + col] = f2bf((acc[i][j][r] + bvv) * SC2);
            } else if (sel == 1) {
#pragma unroll
                for (int r = 0; r < 4; r++)
                    Ko[(size_t)(rowb + r) * 1024 + (col - 1024)] = f2bf(acc[i][j][r] + bvv);
            } else {
                int cc = col - 2048;
                int bb = rowb >> 11;
                int sp = ((m0 + wm * 64) & 2047) + (i >> 1) * 32 + l4 * 8 + (i & 1) * 4;
                int hh = cc >> 6, dd = cc & 63;
                ushort4 o;
                o.x = f2bf(acc[i][j][0] + bvv);
                o.y = f2bf(acc[i][j][1] + bvv);
                o.z = f2bf(acc[i][j][2] + bvv);
                o.w = f2bf(acc[i][j][3] + bvv);
                *(ushort4*)(Vo + ((size_t)((bb * 16 + hh) * 64 + dd)) * 2048 + sp) = o;
            }
        }
    }
}

// ---------------- output projection GEMM (R8-proven, fp32 out) ----------------
__global__ __launch_bounds__(256, 2) void gemm_o(
        const u16* __restrict__ A, const u16* __restrict__ W,
        const float* __restrict__ bias, float* __restrict__ out) {
    __shared__ __align__(16) u16 As[2][128 * 32];
    __shared__ __align__(16) u16 Bs[2][128 * 32];
    const int tid = threadIdx.x;
    const int lane = tid & 63;
    const int w = tid >> 6, wm = w >> 1, wn = w & 1;
    const int l15 = lane & 15, l4 = lane >> 4;
    int v = (blockIdx.x & 7) * 64 + (blockIdx.x >> 3);
    int vy = v >> 3, vx = v & 7;
    const int m0 = vy * 128, n0 = vx * 128;

    f32x4 acc[4][4];
#pragma unroll
    for (int i = 0; i < 4; i++)
#pragma unroll
        for (int j = 0; j < 4; j++) acc[i][j] = f32x4{0.f, 0.f, 0.f, 0.f};

#define O_STAGE(buf, kt) do {                                              \
    _Pragma("unroll")                                                      \
    for (int i_ = 0; i_ < 2; i_++) {                                       \
        int c_ = tid + i_ * 256;                                           \
        int row_ = c_ >> 2, slot_ = c_ & 3;                                \
        int cc_ = slot_ ^ ((row_ >> 1) & 3);                               \
        GLL16(A + (size_t)(m0 + row_) * 1024 + (kt) + cc_ * 8, As[buf] + c_ * 8); \
    }                                                                      \
    _Pragma("unroll")                                                      \
    for (int i_ = 0; i_ < 2; i_++) {                                       \
        int c_ = tid + i_ * 256;                                           \
        int row_ = c_ >> 2, slot_ = c_ & 3;                                \
        int cc_ = slot_ ^ ((row_ >> 1) & 3);                               \
        GLL16(W + (size_t)(n0 + row_) * 1024 + (kt) + cc_ * 8, Bs[buf] + c_ * 8); \
    }                                                                      \
} while (0)

    O_STAGE(0, 0);
    __syncthreads();

    for (int kt = 0; kt < 1024; kt += 32) {
        const int cur = (kt >> 5) & 1;
        if (kt != 992) O_STAGE(cur ^ 1, kt + 32);

        bf16x8 af[4], bfr[4];
#pragma unroll
        for (int i = 0; i < 4; i++) {
            int row = wm * 64 + i * 16 + l15;
            int slot = l4 ^ ((row >> 1) & 3);
            af[i] = *(const bf16x8*)(As[cur] + row * 32 + slot * 8);
        }
#pragma unroll
        for (int j = 0; j < 4; j++) {
            int row = wn * 64 + j * 16 + l15;
            int slot = l4 ^ ((row >> 1) & 3);
            bfr[j] = *(const bf16x8*)(Bs[cur] + row * 32 + slot * 8);
        }
#pragma unroll
        for (int i = 0; i < 4; i++)
#pragma unroll
            for (int j = 0; j < 4; j++)
                acc[i][j] = __builtin_amdgcn_mfma_f32_16x16x32_bf16(af[i], bfr[j], acc[i][j], 0, 0, 0);
        __syncthreads();
    }
#undef O_STAGE

#pragma unroll
    for (int j = 0; j < 4; j++) {
        int col = n0 + wn * 64 + j * 16 + l15;
        float bvv = bias[col];
#pragma unroll
        for (int i = 0; i < 4; i++) {
            int rowb = m0 + wm * 64 + i * 16 + l4 * 4;
#pragma unroll
            for (int r = 0; r < 4; r++)
                out[(size_t)(rowb + r) * 1024 + col] = acc[i][j][r] + bvv;
        }
    }
}

// ---------------- fused flash attention (exact R8 body; (256,4) occupancy) ----------------
// 1D grid 1024, XCD swizzle (K/V L2-resident). 4 waves x 32 q-rows, KVBLK=64.
// R8-proven loop {STAGE(next) -> compute -> __syncthreads}; vfr stays AFTER
// the softmax (R9/R14 proved hoisting it spills). ONE knob vs R8:
// launch_bounds (256,3)->(256,4). Live set ~84 VGPR << the 128 cap, so no
// spill (R4's spill was hoist+cap combined); 4 blocks/CU now resident
// (LDS 4x32=128<=160 KB) -> other blocks' waves cover each block's barrier
// vmcnt-drain, the dominant stall.
__global__ __launch_bounds__(256, 4) void attn_fused(
        const u16* __restrict__ Q, const u16* __restrict__ K,
        const u16* __restrict__ Vt, const float* __restrict__ mask,
        u16* __restrict__ ctx) {
    __shared__ __align__(16) u16 Ks[2][64 * 64];    // [kv][d], swizzled slots
    __shared__ __align__(16) u16 Vs[2][64 * 64];    // [d][s'], swizzled slots

    const int tid = threadIdx.x, lane = tid & 63, w = tid >> 6;
    const int l15 = lane & 15, l4 = lane >> 4;
    const int bid = blockIdx.x;
    const int inner = bid >> 3;
    const int bh = ((inner >> 4) << 3) | (bid & 7);
    const int b = bh >> 4, h = bh & 15;
    const int qw = (inner & 15) * 128 + w * 32;
    const float THR2 = 8.0f;

    const u16* Qg = Q + (size_t)b * 2048 * 1024 + h * 64;
    const u16* Kg = K + (size_t)b * 2048 * 1024 + h * 64;
    const u16* Vg = Vt + (size_t)bh * 64 * 2048;
    const float* mp = mask + b * 2048;

    // ---- wave-redundant mask scan: 64 lanes x 8 float4 = 2048 ----
    bool anym;
    {
        bool bad = false;
#pragma unroll
        for (int i = 0; i < 8; i++) {
            float4 a = ((const float4*)mp)[lane * 8 + i];
            bad |= (a.x == 0.f) | (a.y == 0.f) | (a.z == 0.f) | (a.w == 0.f);
        }
        anym = (__ballot(bad) != 0ull);
    }

#define STAGE_KV(buf, kvbase) do {                                         \
    _Pragma("unroll")                                                      \
    for (int i_ = 0; i_ < 2; i_++) {                                       \
        int c_ = tid + i_ * 256;                                           \
        int row_ = c_ >> 3, slot_ = c_ & 7;                                \
        int cc_ = slot_ ^ (row_ & 7);                                      \
        GLL16(Kg + (size_t)((kvbase) + row_) * 1024 + cc_ * 8, Ks[buf] + c_ * 8); \
    }                                                                      \
    _Pragma("unroll")                                                      \
    for (int i_ = 0; i_ < 2; i_++) {                                       \
        int c_ = tid + i_ * 256;                                           \
        int row_ = c_ >> 3, slot_ = c_ & 7;                                \
        int cc_ = slot_ ^ (row_ & 7);                                      \
        GLL16(Vg + (size_t)row_ * 2048 + (kvbase) + cc_ * 8, Vs[buf] + c_ * 8); \
    }                                                                      \
} while (0)

    // hoist Q fragments (B-operand layout), already scaled by log2e/32
    bf16x8 qfr[2][2];
#pragma unroll
    for (int qi = 0; qi < 2; qi++)
#pragma unroll
        for (int kf = 0; kf < 2; kf++)
            qfr[qi][kf] = *(const bf16x8*)(Qg + (size_t)(qw + qi * 16 + l15) * 1024 + kf * 32 + l4 * 8);

    // q-mask 0/1 flag (cold path only)
    float mq01[2];
#pragma unroll
    for (int qi = 0; qi < 2; qi++)
        mq01[qi] = (mp[qw + qi * 16 + l15] != 0.f) ? 1.f : 0.f;

    float m_run[2] = {0.f, 0.f};
    f32x4 acc_l[2];      // denominator via ones-MFMA
    f32x4 oaccT[4][2];   // O^T: [d-frag][q-frag]
#pragma unroll
    for (int qi = 0; qi < 2; qi++) acc_l[qi] = f32x4{0.f, 0.f, 0.f, 0.f};
#pragma unroll
    for (int df = 0; df < 4; df++)
#pragma unroll
        for (int qi = 0; qi < 2; qi++) oaccT[df][qi] = f32x4{0.f, 0.f, 0.f, 0.f};

    const u32x4 ones4 = u32x4{0x3F803F80u, 0x3F803F80u, 0x3F803F80u, 0x3F803F80u};
    const bf16x8 ones = __builtin_bit_cast(bf16x8, ones4);

    STAGE_KV(0, 0);
    __syncthreads();

    for (int it = 0; it < 32; ++it) {
        const int cur = it & 1;
        const int kv0 = it * 64;

        if (it != 31) STAGE_KV(cur ^ 1, kv0 + 64);

        // ---- S^T = K Q^T (emits base-2 scores; Q pre-scaled) ----
        bf16x8 kfr[4][2];
#pragma unroll
        for (int kvf = 0; kvf < 4; kvf++)
#pragma unroll
            for (int kf = 0; kf < 2; kf++) {
                int row = kvf * 16 + l15;
                int slot = (kf * 4 + l4) ^ (row & 7);
                kfr[kvf][kf] = *(const bf16x8*)(Ks[cur] + row * 64 + slot * 8);
            }
        f32x4 p[4][2];
#pragma unroll
        for (int kvf = 0; kvf < 4; kvf++)
#pragma unroll
            for (int qi = 0; qi < 2; qi++) p[kvf][qi] = f32x4{0.f, 0.f, 0.f, 0.f};
        __builtin_amdgcn_s_setprio(1);
#pragma unroll
        for (int kvf = 0; kvf < 4; kvf++)
#pragma unroll
            for (int qi = 0; qi < 2; qi++)
#pragma unroll
                for (int kf = 0; kf < 2; kf++)
                    p[kvf][qi] = __builtin_amdgcn_mfma_f32_16x16x32_bf16(kfr[kvf][kf], qfr[qi][kf], p[kvf][qi], 0, 0, 0);
        __builtin_amdgcn_s_setprio(0);

        // ---- cold masked path: p = p*mq01 + kbias ----
        if (anym) {
            float4 mkv[4];
#pragma unroll
            for (int kvf = 0; kvf < 4; kvf++)
                mkv[kvf] = ((const float4*)(mp + kv0))[kvf * 4 + l4];
#pragma unroll
            for (int qi = 0; qi < 2; qi++)
#pragma unroll
                for (int kvf = 0; kvf < 4; kvf++)
#pragma unroll
                    for (int r = 0; r < 4; r++) {
                        float bb = (mkv[kvf][r] != 0.f) ? 0.f : -1e12f;
                        p[kvf][qi][r] = __builtin_fmaf(p[kvf][qi][r], mq01[qi], bb);
                    }
        }

        // ---- lane-local maxima; guard vs m_run + THR ----
        float t[2];
#pragma unroll
        for (int qi = 0; qi < 2; qi++) {
            float a0 = fmaxf(fmaxf(p[0][qi][0], p[0][qi][1]), fmaxf(p[0][qi][2], p[0][qi][3]));
            float a1 = fmaxf(fmaxf(p[1][qi][0], p[1][qi][1]), fmaxf(p[1][qi][2], p[1][qi][3]));
            float a2 = fmaxf(fmaxf(p[2][qi][0], p[2][qi][1]), fmaxf(p[2][qi][2], p[2][qi][3]));
            float a3 = fmaxf(fmaxf(p[3][qi][0], p[3][qi][1]), fmaxf(p[3][qi][2], p[3][qi][3]));
            t[qi] = fmaxf(fmaxf(a0, a1), fmaxf(a2, a3));
        }
        if (!__all((t[0] <= m_run[0] + THR2) && (t[1] <= m_run[1] + THR2))) {
            // cold rescale: cross-lane max, update m_run, scale accumulators
#pragma unroll
            for (int qi = 0; qi < 2; qi++) {
                float tt = fmaxf(t[qi], __shfl_xor(t[qi], 16));
                tt = fmaxf(tt, __shfl_xor(tt, 32));
                float mn = fmaxf(m_run[qi], tt);
                float sc = __builtin_amdgcn_exp2f(m_run[qi] - mn);
                m_run[qi] = mn;
                acc_l[qi] *= sc;
#pragma unroll
                for (int df = 0; df < 4; df++) oaccT[df][qi] *= sc;
            }
        }
        // ---- exp2; m_run==0 fast path has no subtract ----
        if (__all((m_run[0] == 0.f) & (m_run[1] == 0.f))) {
#pragma unroll
            for (int qi = 0; qi < 2; qi++)
#pragma unroll
                for (int kvf = 0; kvf < 4; kvf++)
#pragma unroll
                    for (int r = 0; r < 4; r++)
                        p[kvf][qi][r] = __builtin_amdgcn_exp2f(p[kvf][qi][r]);
        } else {
#pragma unroll
            for (int qi = 0; qi < 2; qi++)
#pragma unroll
                for (int kvf = 0; kvf < 4; kvf++)
#pragma unroll
                    for (int r = 0; r < 4; r++)
                        p[kvf][qi][r] = __builtin_amdgcn_exp2f(p[kvf][qi][r] - m_run[qi]);
        }

        // ---- pb = lane-local P quads packed to bf16 ----
        bf16x8 pb[2][2];
#pragma unroll
        for (int qi = 0; qi < 2; qi++)
#pragma unroll
            for (int kf = 0; kf < 2; kf++) {
                u32x4 tq;
                tq.x = cvtpk(p[2 * kf][qi][0], p[2 * kf][qi][1]);
                tq.y = cvtpk(p[2 * kf][qi][2], p[2 * kf][qi][3]);
                tq.z = cvtpk(p[2 * kf + 1][qi][0], p[2 * kf + 1][qi][1]);
                tq.w = cvtpk(p[2 * kf + 1][qi][2], p[2 * kf + 1][qi][3]);
                pb[qi][kf] = __builtin_bit_cast(bf16x8, tq);
            }

        // V fragments after softmax (kept out of the VALU-phase live set —
        // R9/R14 proved hoisting them spills)
        bf16x8 vfr[4][2];
#pragma unroll
        for (int df = 0; df < 4; df++)
#pragma unroll
            for (int kf = 0; kf < 2; kf++) {
                int row = df * 16 + l15;
                int slot = (kf * 4 + l4) ^ (row & 7);
                vfr[df][kf] = *(const bf16x8*)(Vs[cur] + row * 64 + slot * 8);
            }

        // ---- O^T += V^T P^T ; l += ones^T P^T ----
        __builtin_amdgcn_s_setprio(1);
#pragma unroll
        for (int df = 0; df < 4; df++)
#pragma unroll
            for (int qi = 0; qi < 2; qi++)
#pragma unroll
                for (int kf = 0; kf < 2; kf++)
                    oaccT[df][qi] = __builtin_amdgcn_mfma_f32_16x16x32_bf16(vfr[df][kf], pb[qi][kf], oaccT[df][qi], 0, 0, 0);
#pragma unroll
        for (int qi = 0; qi < 2; qi++)
#pragma unroll
            for (int kf = 0; kf < 2; kf++)
                acc_l[qi] = __builtin_amdgcn_mfma_f32_16x16x32_bf16(ones, pb[qi][kf], acc_l[qi], 0, 0, 0);
        __builtin_amdgcn_s_setprio(0);

        __syncthreads();   // drains prefetch vmcnt + protects both dbuf halves
    }

    // ---- epilogue: ctx[token][h*64+d] = O^T / l ----
#pragma unroll
    for (int qi = 0; qi < 2; qi++) {
        float rl = 1.0f / acc_l[qi][0];
        int tok = qw + qi * 16 + l15;
#pragma unroll
        for (int df = 0; df < 4; df++) {
            uint2 o;
            o.x = cvtpk(oaccT[df][qi][0] * rl, oaccT[df][qi][1] * rl);
            o.y = cvtpk(oaccT[df][qi][2] * rl, oaccT[df][qi][3] * rl);
            *(uint2*)(ctx + (size_t)(b * 2048 + tok) * 1024 + h * 64 + df * 16 + l4 * 4) = o;
        }
    }
#undef STAGE_KV
}

extern "C" void kernel_launch(void* const* d_in, const int* in_sizes, int n_in,
                              void* d_out, int out_size, void* d_ws, size_t ws_size,
                              hipStream_t stream) {
    const float* hs    = (const float*)d_in[0];
    const float* masks = (const float*)d_in[1];
    const float* Wq = (const float*)d_in[2];
    const float* bq = (const float*)d_in[3];
    const float* Wk = (const float*)d_in[4];
    const float* bk = (const float*)d_in[5];
    const float* Wv = (const float*)d_in[6];
    const float* bv = (const float*)d_in[7];
    const float* Wo = (const float*)d_in[8];
    const float* bo = (const float*)d_in[9];

    const int NT = 4 * 2048;   // 8192 tokens
    const int H = 1024;

    u16* hs_b = (u16*)d_ws;                       // [8192,1024]
    u16* w_b  = hs_b + (size_t)NT * H;            // [Wq|Wk|Wv|Wo] 4x[1024,1024]
    u16* wo_b = w_b + (size_t)3 * H * H;
    u16* Qb   = w_b + (size_t)4 * H * H;          // [8192,1024] (pre-scaled)
    u16* Kb   = Qb + (size_t)NT * H;              // [8192,1024]
    u16* Vtb  = Kb + (size_t)NT * H;              // [64][64][2048] s'-permuted
    u16* Cb   = hs_b;                             // attn output reuses hidden buffer

    // one fused conversion dispatch: hs + 4 weights into contiguous ws region
    cvt_all<<<12288, 256, 0, stream>>>(hs, Wq, Wk, Wv, Wo, hs_b);

    gemm_qkv<<<1536, 256, 0, stream>>>(hs_b, w_b, bq, bk, bv, Qb, Kb, Vtb);

    attn_fused<<<1024, 256, 0, stream>>>(Qb, Kb, Vtb, masks, Cb);

    gemm_o<<<512, 256, 0, stream>>>(Cb, wo_b, bo, (float*)d_out);
}

// Round 16
// 195.420 us; speedup vs baseline: 1.1111x; 1.0298x over previous
//
#include <hip/hip_runtime.h>
#include <hip/hip_bf16.h>
#include <stdint.h>

typedef unsigned short u16;
typedef __attribute__((ext_vector_type(4))) float f32x4;
typedef __attribute__((ext_vector_type(8))) short bf16x8;
typedef __attribute__((ext_vector_type(4))) unsigned int u32x4;

#define GLL16(src, dst) __builtin_amdgcn_global_load_lds( \
    (const __attribute__((address_space(1))) void*)(src), \
    (__attribute__((address_space(3))) void*)(dst), 16, 0, 0)

static __device__ __forceinline__ u16 f2bf(float x) {
    uint32_t u = __builtin_bit_cast(uint32_t, x);
    u += 0x7fffu + ((u >> 16) & 1u);
    return (u16)(u >> 16);
}

static __device__ __forceinline__ uint32_t cvtpk(float lo, float hi) {
    uint32_t r;
    asm("v_cvt_pk_bf16_f32 %0, %1, %2" : "=v"(r) : "v"(lo), "v"(hi));
    return r;
}

// ---------------- fused fp32 -> bf16 conversion: hs + all 4 weights ----------------
// dst contiguous in ws: [hs_b (8192x1024) | Wq | Wk | Wv | Wo]. One dispatch
// (R14-verified: saves ~3 us vs two dispatches).
__global__ __launch_bounds__(256) void cvt_all(
        const float* __restrict__ hs, const float* __restrict__ w0,
        const float* __restrict__ w1, const float* __restrict__ w2,
        const float* __restrict__ w3, u16* __restrict__ dst) {
    int blk = blockIdx.x;
    const float* src;
    if (blk < 8192) {
        src = hs + (size_t)blk * 1024;
    } else {
        int j = blk - 8192;
        int wsel = j >> 10;
        const float* w = (wsel == 0) ? w0 : (wsel == 1) ? w1 : (wsel == 2) ? w2 : w3;
        src = w + (size_t)(j & 1023) * 1024;
    }
    int i = threadIdx.x;
    float4 v = ((const float4*)src)[i];
    ushort4 o;
    o.x = f2bf(v.x); o.y = f2bf(v.y); o.z = f2bf(v.z); o.w = f2bf(v.w);
    ((ushort4*)(dst + (size_t)blk * 1024))[i] = o;
}

// ---------------- fused QKV GEMM (R8-proven) ----------------
__global__ __launch_bounds__(256, 2) void gemm_qkv(
        const u16* __restrict__ A, const u16* __restrict__ W,
        const float* __restrict__ bq, const float* __restrict__ bk,
        const float* __restrict__ bv,
        u16* __restrict__ Qo, u16* __restrict__ Ko, u16* __restrict__ Vo) {
    __shared__ __align__(16) u16 As[2][128 * 32];
    __shared__ __align__(16) u16 Bs[2][128 * 32];
    const int tid = threadIdx.x;
    const int lane = tid & 63;
    const int w = tid >> 6, wm = w >> 1, wn = w & 1;
    const int l15 = lane & 15, l4 = lane >> 4;
    int v = (blockIdx.x & 7) * 192 + (blockIdx.x >> 3);
    int vy = v / 24, vx = v - vy * 24;
    const int m0 = vy * 128, n0 = vx * 128;
    const float SC2 = 0.03125f * 1.44269504088896f;

    f32x4 acc[4][4];
#pragma unroll
    for (int i = 0; i < 4; i++)
#pragma unroll
        for (int j = 0; j < 4; j++) acc[i][j] = f32x4{0.f, 0.f, 0.f, 0.f};

#define QKV_STAGE(buf, kt) do {                                            \
    _Pragma("unroll")                                                      \
    for (int i_ = 0; i_ < 2; i_++) {                                       \
        int c_ = tid + i_ * 256;                                           \
        int row_ = c_ >> 2, slot_ = c_ & 3;                                \
        int cc_ = slot_ ^ ((row_ >> 1) & 3);                               \
        GLL16(A + (size_t)(m0 + row_) * 1024 + (kt) + cc_ * 8, As[buf] + c_ * 8); \
    }                                                                      \
    _Pragma("unroll")                                                      \
    for (int i_ = 0; i_ < 2; i_++) {                                       \
        int c_ = tid + i_ * 256;                                           \
        int row_ = c_ >> 2, slot_ = c_ & 3;                                \
        int cc_ = slot_ ^ ((row_ >> 1) & 3);                               \
        GLL16(W + (size_t)(n0 + row_) * 1024 + (kt) + cc_ * 8, Bs[buf] + c_ * 8); \
    }                                                                      \
} while (0)

    QKV_STAGE(0, 0);
    __syncthreads();

    for (int kt = 0; kt < 1024; kt += 32) {
        const int cur = (kt >> 5) & 1;
        if (kt != 992) QKV_STAGE(cur ^ 1, kt + 32);

        bf16x8 af[4], bfr[4];
#pragma unroll
        for (int i = 0; i < 4; i++) {
            int row = wm * 64 + i * 16 + l15;
            int slot = l4 ^ ((row >> 1) & 3);
            af[i] = *(const bf16x8*)(As[cur] + row * 32 + slot * 8);
        }
#pragma unroll
        for (int j = 0; j < 4; j++) {
            int row = wn * 64 + j * 16 + l15;
            int slot = l4 ^ ((row >> 1) & 3);
            bfr[j] = *(const bf16x8*)(Bs[cur] + row * 32 + slot * 8);
        }
#pragma unroll
        for (int i = 0; i < 4; i++)
#pragma unroll
            for (int j = 0; j < 4; j++)
                acc[i][j] = __builtin_amdgcn_mfma_f32_16x16x32_bf16(af[i], bfr[j], acc[i][j], 0, 0, 0);
        __syncthreads();
    }
#undef QKV_STAGE

#pragma unroll
    for (int j = 0; j < 4; j++) {
        int col = n0 + wn * 64 + j * 16 + l15;
        int sel = col >> 10;
        float bvv = (sel == 0) ? bq[col] : (sel == 1) ? bk[col - 1024] : bv[col - 2048];
#pragma unroll
        for (int i = 0; i < 4; i++) {
            int rowb = m0 + wm * 64 + i * 16 + l4 * 4;
            if (sel == 0) {
#pragma unroll
                for (int r = 0; r < 4; r++)
                    Qo[(size_t)(rowb + r) * 1024 + col] = f2bf((acc[i][j][r] + bvv) * SC2);
            } else if (sel == 1) {
#pragma unroll
                for (int r = 0; r < 4; r++)
                    Ko[(size_t)(rowb + r) * 1024 + (col - 1024)] = f2bf(acc[i][j][r] + bvv);
            } else {
                int cc = col - 2048;
                int bb = rowb >> 11;
                int sp = ((m0 + wm * 64) & 2047) + (i >> 1) * 32 + l4 * 8 + (i & 1) * 4;
                int hh = cc >> 6, dd = cc & 63;
                ushort4 o;
                o.x = f2bf(acc[i][j][0] + bvv);
                o.y = f2bf(acc[i][j][1] + bvv);
                o.z = f2bf(acc[i][j][2] + bvv);
                o.w = f2bf(acc[i][j][3] + bvv);
                *(ushort4*)(Vo + ((size_t)((bb * 16 + hh) * 64 + dd)) * 2048 + sp) = o;
            }
        }
    }
}

// ---------------- output projection GEMM (R8-proven, fp32 out) ----------------
__global__ __launch_bounds__(256, 2) void gemm_o(
        const u16* __restrict__ A, const u16* __restrict__ W,
        const float* __restrict__ bias, float* __restrict__ out) {
    __shared__ __align__(16) u16 As[2][128 * 32];
    __shared__ __align__(16) u16 Bs[2][128 * 32];
    const int tid = threadIdx.x;
    const int lane = tid & 63;
    const int w = tid >> 6, wm = w >> 1, wn = w & 1;
    const int l15 = lane & 15, l4 = lane >> 4;
    int v = (blockIdx.x & 7) * 64 + (blockIdx.x >> 3);
    int vy = v >> 3, vx = v & 7;
    const int m0 = vy * 128, n0 = vx * 128;

    f32x4 acc[4][4];
#pragma unroll
    for (int i = 0; i < 4; i++)
#pragma unroll
        for (int j = 0; j < 4; j++) acc[i][j] = f32x4{0.f, 0.f, 0.f, 0.f};

#define O_STAGE(buf, kt) do {                                              \
    _Pragma("unroll")                                                      \
    for (int i_ = 0; i_ < 2; i_++) {                                       \
        int c_ = tid + i_ * 256;                                           \
        int row_ = c_ >> 2, slot_ = c_ & 3;                                \
        int cc_ = slot_ ^ ((row_ >> 1) & 3);                               \
        GLL16(A + (size_t)(m0 + row_) * 1024 + (kt) + cc_ * 8, As[buf] + c_ * 8); \
    }                                                                      \
    _Pragma("unroll")                                                      \
    for (int i_ = 0; i_ < 2; i_++) {                                       \
        int c_ = tid + i_ * 256;                                           \
        int row_ = c_ >> 2, slot_ = c_ & 3;                                \
        int cc_ = slot_ ^ ((row_ >> 1) & 3);                               \
        GLL16(W + (size_t)(n0 + row_) * 1024 + (kt) + cc_ * 8, Bs[buf] + c_ * 8); \
    }                                                                      \
} while (0)

    O_STAGE(0, 0);
    __syncthreads();

    for (int kt = 0; kt < 1024; kt += 32) {
        const int cur = (kt >> 5) & 1;
        if (kt != 992) O_STAGE(cur ^ 1, kt + 32);

        bf16x8 af[4], bfr[4];
#pragma unroll
        for (int i = 0; i < 4; i++) {
            int row = wm * 64 + i * 16 + l15;
            int slot = l4 ^ ((row >> 1) & 3);
            af[i] = *(const bf16x8*)(As[cur] + row * 32 + slot * 8);
        }
#pragma unroll
        for (int j = 0; j < 4; j++) {
            int row = wn * 64 + j * 16 + l15;
            int slot = l4 ^ ((row >> 1) & 3);
            bfr[j] = *(const bf16x8*)(Bs[cur] + row * 32 + slot * 8);
        }
#pragma unroll
        for (int i = 0; i < 4; i++)
#pragma unroll
            for (int j = 0; j < 4; j++)
                acc[i][j] = __builtin_amdgcn_mfma_f32_16x16x32_bf16(af[i], bfr[j], acc[i][j], 0, 0, 0);
        __syncthreads();
    }
#undef O_STAGE

#pragma unroll
    for (int j = 0; j < 4; j++) {
        int col = n0 + wn * 64 + j * 16 + l15;
        float bvv = bias[col];
#pragma unroll
        for (int i = 0; i < 4; i++) {
            int rowb = m0 + wm * 64 + i * 16 + l4 * 4;
#pragma unroll
            for (int r = 0; r < 4; r++)
                out[(size_t)(rowb + r) * 1024 + col] = acc[i][j][r] + bvv;
        }
    }
}

// ---------------- fused flash attention (exact R8-proven kernel, (256,3)) ----------------
// 1D grid 1024, XCD swizzle (K/V L2-resident). 4 waves x 32 q-rows, KVBLK=64.
// {STAGE(next) -> compute -> __syncthreads}; vfr after softmax. Design space
// closed by measurement: (256,3) optimal (2=worse pipeline, 4=spill);
// KVBLK 64 (128 re-introduced bank conflicts); 128 q/block (256 spills);
// LDS dbuf (LDS-free latency-bound; counted-vmcnt regressed); vfr post-softmax
// (hoist spills). Softmax: prescaled-Q base-2, zero cross-lane hot path,
// ones-MFMA denominator, defer-max.
__global__ __launch_bounds__(256, 3) void attn_fused(
        const u16* __restrict__ Q, const u16* __restrict__ K,
        const u16* __restrict__ Vt, const float* __restrict__ mask,
        u16* __restrict__ ctx) {
    __shared__ __align__(16) u16 Ks[2][64 * 64];    // [kv][d], swizzled slots
    __shared__ __align__(16) u16 Vs[2][64 * 64];    // [d][s'], swizzled slots

    const int tid = threadIdx.x, lane = tid & 63, w = tid >> 6;
    const int l15 = lane & 15, l4 = lane >> 4;
    const int bid = blockIdx.x;
    const int inner = bid >> 3;
    const int bh = ((inner >> 4) << 3) | (bid & 7);
    const int b = bh >> 4, h = bh & 15;
    const int qw = (inner & 15) * 128 + w * 32;
    const float THR2 = 8.0f;

    const u16* Qg = Q + (size_t)b * 2048 * 1024 + h * 64;
    const u16* Kg = K + (size_t)b * 2048 * 1024 + h * 64;
    const u16* Vg = Vt + (size_t)bh * 64 * 2048;
    const float* mp = mask + b * 2048;

    // ---- wave-redundant mask scan: 64 lanes x 8 float4 = 2048 ----
    bool anym;
    {
        bool bad = false;
#pragma unroll
        for (int i = 0; i < 8; i++) {
            float4 a = ((const float4*)mp)[lane * 8 + i];
            bad |= (a.x == 0.f) | (a.y == 0.f) | (a.z == 0.f) | (a.w == 0.f);
        }
        anym = (__ballot(bad) != 0ull);
    }

#define STAGE_KV(buf, kvbase) do {                                         \
    _Pragma("unroll")                                                      \
    for (int i_ = 0; i_ < 2; i_++) {                                       \
        int c_ = tid + i_ * 256;                                           \
        int row_ = c_ >> 3, slot_ = c_ & 7;                                \
        int cc_ = slot_ ^ (row_ & 7);                                      \
        GLL16(Kg + (size_t)((kvbase) + row_) * 1024 + cc_ * 8, Ks[buf] + c_ * 8); \
    }                                                                      \
    _Pragma("unroll")                                                      \
    for (int i_ = 0; i_ < 2; i_++) {                                       \
        int c_ = tid + i_ * 256;                                           \
        int row_ = c_ >> 3, slot_ = c_ & 7;                                \
        int cc_ = slot_ ^ (row_ & 7);                                      \
        GLL16(Vg + (size_t)row_ * 2048 + (kvbase) + cc_ * 8, Vs[buf] + c_ * 8); \
    }                                                                      \
} while (0)

    // hoist Q fragments (B-operand layout), already scaled by log2e/32
    bf16x8 qfr[2][2];
#pragma unroll
    for (int qi = 0; qi < 2; qi++)
#pragma unroll
        for (int kf = 0; kf < 2; kf++)
            qfr[qi][kf] = *(const bf16x8*)(Qg + (size_t)(qw + qi * 16 + l15) * 1024 + kf * 32 + l4 * 8);

    // q-mask 0/1 flag (cold path only)
    float mq01[2];
#pragma unroll
    for (int qi = 0; qi < 2; qi++)
        mq01[qi] = (mp[qw + qi * 16 + l15] != 0.f) ? 1.f : 0.f;

    float m_run[2] = {0.f, 0.f};
    f32x4 acc_l[2];      // denominator via ones-MFMA
    f32x4 oaccT[4][2];   // O^T: [d-frag][q-frag]
#pragma unroll
    for (int qi = 0; qi < 2; qi++) acc_l[qi] = f32x4{0.f, 0.f, 0.f, 0.f};
#pragma unroll
    for (int df = 0; df < 4; df++)
#pragma unroll
        for (int qi = 0; qi < 2; qi++) oaccT[df][qi] = f32x4{0.f, 0.f, 0.f, 0.f};

    const u32x4 ones4 = u32x4{0x3F803F80u, 0x3F803F80u, 0x3F803F80u, 0x3F803F80u};
    const bf16x8 ones = __builtin_bit_cast(bf16x8, ones4);

    STAGE_KV(0, 0);
    __syncthreads();

    for (int it = 0; it < 32; ++it) {
        const int cur = it & 1;
        const int kv0 = it * 64;

        if (it != 31) STAGE_KV(cur ^ 1, kv0 + 64);

        // ---- S^T = K Q^T (emits base-2 scores; Q pre-scaled) ----
        bf16x8 kfr[4][2];
#pragma unroll
        for (int kvf = 0; kvf < 4; kvf++)
#pragma unroll
            for (int kf = 0; kf < 2; kf++) {
                int row = kvf * 16 + l15;
                int slot = (kf * 4 + l4) ^ (row & 7);
                kfr[kvf][kf] = *(const bf16x8*)(Ks[cur] + row * 64 + slot * 8);
            }
        f32x4 p[4][2];
#pragma unroll
        for (int kvf = 0; kvf < 4; kvf++)
#pragma unroll
            for (int qi = 0; qi < 2; qi++) p[kvf][qi] = f32x4{0.f, 0.f, 0.f, 0.f};
        __builtin_amdgcn_s_setprio(1);
#pragma unroll
        for (int kvf = 0; kvf < 4; kvf++)
#pragma unroll
            for (int qi = 0; qi < 2; qi++)
#pragma unroll
                for (int kf = 0; kf < 2; kf++)
                    p[kvf][qi] = __builtin_amdgcn_mfma_f32_16x16x32_bf16(kfr[kvf][kf], qfr[qi][kf], p[kvf][qi], 0, 0, 0);
        __builtin_amdgcn_s_setprio(0);

        // ---- cold masked path: p = p*mq01 + kbias ----
        if (anym) {
            float4 mkv[4];
#pragma unroll
            for (int kvf = 0; kvf < 4; kvf++)
                mkv[kvf] = ((const float4*)(mp + kv0))[kvf * 4 + l4];
#pragma unroll
            for (int qi = 0; qi < 2; qi++)
#pragma unroll
                for (int kvf = 0; kvf < 4; kvf++)
#pragma unroll
                    for (int r = 0; r < 4; r++) {
                        float bb = (mkv[kvf][r] != 0.f) ? 0.f : -1e12f;
                        p[kvf][qi][r] = __builtin_fmaf(p[kvf][qi][r], mq01[qi], bb);
                    }
        }

        // ---- lane-local maxima; guard vs m_run + THR ----
        float t[2];
#pragma unroll
        for (int qi = 0; qi < 2; qi++) {
            float a0 = fmaxf(fmaxf(p[0][qi][0], p[0][qi][1]), fmaxf(p[0][qi][2], p[0][qi][3]));
            float a1 = fmaxf(fmaxf(p[1][qi][0], p[1][qi][1]), fmaxf(p[1][qi][2], p[1][qi][3]));
            float a2 = fmaxf(fmaxf(p[2][qi][0], p[2][qi][1]), fmaxf(p[2][qi][2], p[2][qi][3]));
            float a3 = fmaxf(fmaxf(p[3][qi][0], p[3][qi][1]), fmaxf(p[3][qi][2], p[3][qi][3]));
            t[qi] = fmaxf(fmaxf(a0, a1), fmaxf(a2, a3));
        }
        if (!__all((t[0] <= m_run[0] + THR2) && (t[1] <= m_run[1] + THR2))) {
            // cold rescale: cross-lane max, update m_run, scale accumulators
#pragma unroll
            for (int qi = 0; qi < 2; qi++) {
                float tt = fmaxf(t[qi], __shfl_xor(t[qi], 16));
                tt = fmaxf(tt, __shfl_xor(tt, 32));
                float mn = fmaxf(m_run[qi], tt);
                float sc = __builtin_amdgcn_exp2f(m_run[qi] - mn);
                m_run[qi] = mn;
                acc_l[qi] *= sc;
#pragma unroll
                for (int df = 0; df < 4; df++) oaccT[df][qi] *= sc;
            }
        }
        // ---- exp2; m_run==0 fast path has no subtract ----
        if (__all((m_run[0] == 0.f) & (m_run[1] == 0.f))) {
#pragma unroll
            for (int qi = 0; qi < 2; qi++)
#pragma unroll
                for (int kvf = 0; kvf < 4; kvf++)
#pragma unroll
                    for (int r = 0; r < 4; r++)
                        p[kvf][qi][r] = __builtin_amdgcn_exp2f(p[kvf][qi][r]);
        } else {
#pragma unroll
            for (int qi = 0; qi < 2; qi++)
#pragma unroll
                for (int kvf = 0; kvf < 4; kvf++)
#pragma unroll
                    for (int r = 0; r < 4; r++)
                        p[kvf][qi][r] = __builtin_amdgcn_exp2f(p[kvf][qi][r] - m_run[qi]);
        }

        // ---- pb = lane-local P quads packed to bf16 ----
        bf16x8 pb[2][2];
#pragma unroll
        for (int qi = 0; qi < 2; qi++)
#pragma unroll
            for (int kf = 0; kf < 2; kf++) {
                u32x4 tq;
                tq.x = cvtpk(p[2 * kf][qi][0], p[2 * kf][qi][1]);
                tq.y = cvtpk(p[2 * kf][qi][2], p[2 * kf][qi][3]);
                tq.z = cvtpk(p[2 * kf + 1][qi][0], p[2 * kf + 1][qi][1]);
                tq.w = cvtpk(p[2 * kf + 1][qi][2], p[2 * kf + 1][qi][3]);
                pb[qi][kf] = __builtin_bit_cast(bf16x8, tq);
            }

        // V fragments after softmax (kept out of the VALU-phase live set)
        bf16x8 vfr[4][2];
#pragma unroll
        for (int df = 0; df < 4; df++)
#pragma unroll
            for (int kf = 0; kf < 2; kf++) {
                int row = df * 16 + l15;
                int slot = (kf * 4 + l4) ^ (row & 7);
                vfr[df][kf] = *(const bf16x8*)(Vs[cur] + row * 64 + slot * 8);
            }

        // ---- O^T += V^T P^T ; l += ones^T P^T ----
        __builtin_amdgcn_s_setprio(1);
#pragma unroll
        for (int df = 0; df < 4; df++)
#pragma unroll
            for (int qi = 0; qi < 2; qi++)
#pragma unroll
                for (int kf = 0; kf < 2; kf++)
                    oaccT[df][qi] = __builtin_amdgcn_mfma_f32_16x16x32_bf16(vfr[df][kf], pb[qi][kf], oaccT[df][qi], 0, 0, 0);
#pragma unroll
        for (int qi = 0; qi < 2; qi++)
#pragma unroll
            for (int kf = 0; kf < 2; kf++)
                acc_l[qi] = __builtin_amdgcn_mfma_f32_16x16x32_bf16(ones, pb[qi][kf], acc_l[qi], 0, 0, 0);
        __builtin_amdgcn_s_setprio(0);

        __syncthreads();   // drains prefetch vmcnt + protects both dbuf halves
    }

    // ---- epilogue: ctx[token][h*64+d] = O^T / l ----
#pragma unroll
    for (int qi = 0; qi < 2; qi++) {
        float rl = 1.0f / acc_l[qi][0];
        int tok = qw + qi * 16 + l15;
#pragma unroll
        for (int df = 0; df < 4; df++) {
            uint2 o;
            o.x = cvtpk(oaccT[df][qi][0] * rl, oaccT[df][qi][1] * rl);
            o.y = cvtpk(oaccT[df][qi][2] * rl, oaccT[df][qi][3] * rl);
            *(uint2*)(ctx + (size_t)(b * 2048 + tok) * 1024 + h * 64 + df * 16 + l4 * 4) = o;
        }
    }
#undef STAGE_KV
}

extern "C" void kernel_launch(void* const* d_in, const int* in_sizes, int n_in,
                              void* d_out, int out_size, void* d_ws, size_t ws_size,
                              hipStream_t stream) {
    const float* hs    = (const float*)d_in[0];
    const float* masks = (const float*)d_in[1];
    const float* Wq = (const float*)d_in[2];
    const float* bq = (const float*)d_in[3];
    const float* Wk = (const float*)d_in[4];
    const float* bk = (const float*)d_in[5];
    const float* Wv = (const float*)d_in[6];
    const float* bv = (const float*)d_in[7];
    const float* Wo = (const float*)d_in[8];
    const float* bo = (const float*)d_in[9];

    const int NT = 4 * 2048;   // 8192 tokens
    const int H = 1024;

    u16* hs_b = (u16*)d_ws;                       // [8192,1024]
    u16* w_b  = hs_b + (size_t)NT * H;            // [Wq|Wk|Wv|Wo] 4x[1024,1024]
    u16* wo_b = w_b + (size_t)3 * H * H;
    u16* Qb   = w_b + (size_t)4 * H * H;          // [8192,1024] (pre-scaled)
    u16* Kb   = Qb + (size_t)NT * H;              // [8192,1024]
    u16* Vtb  = Kb + (size_t)NT * H;              // [64][64][2048] s'-permuted
    u16* Cb   = hs_b;                             // attn output reuses hidden buffer

    // one fused conversion dispatch: hs + 4 weights into contiguous ws region
    cvt_all<<<12288, 256, 0, stream>>>(hs, Wq, Wk, Wv, Wo, hs_b);

    gemm_qkv<<<1536, 256, 0, stream>>>(hs_b, w_b, bq, bk, bv, Qb, Kb, Vtb);

    attn_fused<<<1024, 256, 0, stream>>>(Qb, Kb, Vtb, masks, Cb);

    gemm_o<<<512, 256, 0, stream>>>(Cb, wo_b, bo, (float*)d_out);
}